// Round 1
// 1699.723 us; speedup vs baseline: 1.0066x; 1.0066x over previous
//
#include <hip/hip_runtime.h>

// LSTM B=128,T=1024,H=128,D=64,L=3 — fused, layer-pipelined, R7.
// R7 change: __launch_bounds__(512,2) -> __launch_bounds__(512).
// The (512,2) hint capped the allocator at ~128 VGPRs (observed 120), which
// cannot hold the persistent weight fragments (bwh 64 VGPR + bwi 64 VGPR for
// layers 1/2) -> compiler spilled/rematerialized weights INSIDE the serial
// recurrence loop. That is the memory-latency stall that made layers 1/2 run
// ~3x slower than layer 0 (occupancy decay 0.82 == layer-0 early exit) with
// all busy counters <8%. With 96 WGs on 256 CUs, 2 blocks/CU buys nothing:
// unlock to the schedulability cap (256 VGPR for an 8-wave block).
// Everything else identical to R6: 96 WGs = 3 layers x 32 groups (NB=4,
// WG=512). Cross-WG y exchange via RELAXED agent-scope atomics (IF$-coherent,
// bypassing non-coherent per-XCD L2s) ordered by vmcnt(0)+flag. CH=16
// steps/chunk. Recurrence core: compressed 1KB h exchange, lgkm-only barrier,
// Whh+Wih B-frags in VGPRs.

#define BATCH 128
#define TT    1024
#define HH    128
#define DD    64
#define NB    4
#define CH    16                // chunk steps
#define NG    32                // batch groups per layer
#define BSTR  (CH * 1024 + 8)   // xg LDS bytes per batch

typedef __attribute__((ext_vector_type(4))) float f32x4;
typedef __attribute__((ext_vector_type(8))) short bf16x8;
typedef __attribute__((ext_vector_type(4))) short bf16x4;

union U8 { unsigned long long q[2]; bf16x8 v; };

__device__ inline unsigned short f2bf(float f) {           // RNE
  unsigned u = __builtin_bit_cast(unsigned, f);
  u += 0x7FFFu + ((u >> 16) & 1u);
  return (unsigned short)(u >> 16);
}
__device__ inline float bf2f(unsigned short s) {
  return __builtin_bit_cast(float, (unsigned)s << 16);
}
__device__ inline float fsig(float x) {
  return __builtin_amdgcn_rcpf(1.f + __builtin_amdgcn_exp2f(-1.442695041f * x));
}
__device__ inline float ftanh(float x) {
  return 2.f * __builtin_amdgcn_rcpf(1.f + __builtin_amdgcn_exp2f(-2.885390082f * x)) - 1.f;
}
__device__ inline bf16x8 pack8(f32x4 a, f32x4 b) {
  bf16x8 r;
  r[0]=(short)f2bf(a[0]); r[1]=(short)f2bf(a[1]); r[2]=(short)f2bf(a[2]); r[3]=(short)f2bf(a[3]);
  r[4]=(short)f2bf(b[0]); r[5]=(short)f2bf(b[1]); r[6]=(short)f2bf(b[2]); r[7]=(short)f2bf(b[3]);
  return r;
}
// LDS-only barrier: does NOT drain vmcnt.
__device__ inline void bar_lds() {
  asm volatile("s_waitcnt lgkmcnt(0)\n\ts_barrier" ::: "memory");
}
__device__ inline unsigned long long yload8(const unsigned short* p) {
  return __hip_atomic_load((unsigned long long*)p, __ATOMIC_RELAXED, __HIP_MEMORY_SCOPE_AGENT);
}

__global__ void init_flags(int* f) { if (threadIdx.x < 64) f[threadIdx.x] = 0; }

__global__ __launch_bounds__(512) void lstm_fused(
    const float* __restrict__ x,
    const float* __restrict__ h0, const float* __restrict__ c0,
    const float* __restrict__ Wih0, const float* __restrict__ Whh0,
    const float* __restrict__ bih0, const float* __restrict__ bhh0,
    const float* __restrict__ Wih1, const float* __restrict__ Whh1,
    const float* __restrict__ bih1, const float* __restrict__ bhh1,
    const float* __restrict__ Wih2, const float* __restrict__ Whh2,
    const float* __restrict__ bih2, const float* __restrict__ bhh2,
    const float* __restrict__ Wout, const float* __restrict__ boutp,
    unsigned short* __restrict__ y0, unsigned short* __restrict__ y1,
    float* __restrict__ outp, float* __restrict__ hN, float* __restrict__ cN,
    int* __restrict__ flags)
{
  __shared__ __align__(16) char xqls[NB * BSTR];   // xg chunk [b][t][j][gate]
  __shared__ __align__(16) char hA[2 * 1024];      // h dbuf, compressed A-order

  const int tid = threadIdx.x, wave = tid >> 6, lane = tid & 63;
  const int quad = lane >> 4, l15 = lane & 15;
  const int layer = blockIdx.x / NG, g = blockIdx.x % NG;
  const int bg0 = g * NB;
  const int gb = bg0 + quad;
  const int j = wave * 16 + l15;

  const float *Wih, *Whh, *bih, *bhh;
  const unsigned short* yin = nullptr;
  unsigned short* yout = nullptr;
  if (layer == 0)      { Wih = Wih0; Whh = Whh0; bih = bih0; bhh = bhh0; yout = y0; }
  else if (layer == 1) { Wih = Wih1; Whh = Whh1; bih = bih1; bhh = bhh1; yin = y0; yout = y1; }
  else                 { Wih = Wih2; Whh = Whh2; bih = bih2; bhh = bhh2; yin = y1; }
  const int Kin = (layer == 0) ? DD : HH;

  // Whh B-frags: tile n = q*128 + j, k = quad*8 + kc*32 + e
  bf16x8 bwh[4][4];
#pragma unroll
  for (int q = 0; q < 4; ++q)
#pragma unroll
    for (int kc = 0; kc < 4; ++kc) {
      const float* p = Whh + (size_t)(q * 128 + j) * HH + quad * 8 + kc * 32;
      bwh[q][kc] = pack8(*(const f32x4*)p, *(const f32x4*)(p + 4));
    }
  // Wih B-frags (K = 64 or 128)
  bf16x8 bwi[4][4];
#pragma unroll
  for (int q = 0; q < 4; ++q)
    for (int kc = 0; kc < Kin / 32; ++kc) {
      const float* p = Wih + (size_t)(q * 128 + j) * Kin + quad * 8 + kc * 32;
      bwi[q][kc] = pack8(*(const f32x4*)p, *(const f32x4*)(p + 4));
    }
  float bs[4];
#pragma unroll
  for (int q = 0; q < 4; ++q) bs[q] = bih[q * 128 + j] + bhh[q * 128 + j];

  // compressed h layout: h[b][k] at byte
  //   (k>>5)*256 + (((k>>3)&3)*4 + b)*16 + (k&7)*2
  int off_w = (wave >> 1) * 256 + (((((wave & 1) << 1) | (l15 >> 3)) * 4) + quad) * 16 + (l15 & 7) * 2;
  int off_r = (quad * 4 + (l15 >> 2)) * 16;

  const float* h0l = h0 + (size_t)layer * BATCH * HH;
  const float* c0l = c0 + (size_t)layer * BATCH * HH;
  *(unsigned short*)(hA + off_w) = f2bf(h0l[(size_t)gb * HH + j]);
  float cc = c0l[(size_t)gb * HH + j];

  // projection setup (layer 2)
  f32x4 wv = {0.f, 0.f, 0.f, 0.f};
  float ob = 0.f;
  int prd_off = 0, pbl = 0;
  if (layer == 2 && tid < 128) {
    pbl = tid >> 5;
    int j4 = (tid & 31) * 4;
    wv = *(const f32x4*)(Wout + j4);
    ob = boutp[0];
    prd_off = (j4 >> 5) * 256 + ((((j4 >> 3) & 3) * 4) + pbl) * 16 + (j4 & 7) * 2;
  }

  unsigned short* yo = nullptr;
  if (layer < 2) yo = yout + (size_t)gb * TT * HH + j;   // j even lanes store pairs

  __syncthreads();

  const f32x4 z4 = {0.f, 0.f, 0.f, 0.f};
  float hv = 0.f;

  for (int ck = 0; ck < TT / CH; ++ck) {
    int t0 = ck * CH;

    // ---- consumer: wait for producer chunk (acquire on flag only) ----
    if (layer > 0) {
      if (tid == 0) {
        while (__hip_atomic_load(flags + (layer - 1) * NG + g,
                                 __ATOMIC_ACQUIRE, __HIP_MEMORY_SCOPE_AGENT) <= ck)
          __builtin_amdgcn_s_sleep(1);
      }
      __syncthreads();
    }

    // ---- fused chunk GEMM: 4 M-tiles, tile mt = batch bg0+mt x 16 steps ----
    if (layer == 0) {
      bf16x8 af[4][2];
#pragma unroll
      for (int mt = 0; mt < 4; ++mt) {
        const float* ap = x + ((size_t)(bg0 + mt) * TT + t0 + l15) * DD + quad * 8;
        af[mt][0] = pack8(*(const f32x4*)ap, *(const f32x4*)(ap + 4));
        af[mt][1] = pack8(*(const f32x4*)(ap + 32), *(const f32x4*)(ap + 36));
      }
#pragma unroll
      for (int mt = 0; mt < 4; ++mt) {
        f32x4 acc[4];
#pragma unroll
        for (int q = 0; q < 4; ++q) acc[q] = __builtin_amdgcn_mfma_f32_16x16x32_bf16(af[mt][0], bwi[q][0], z4, 0, 0, 0);
#pragma unroll
        for (int q = 0; q < 4; ++q) acc[q] = __builtin_amdgcn_mfma_f32_16x16x32_bf16(af[mt][1], bwi[q][1], acc[q], 0, 0, 0);
        char* base = xqls + mt * BSTR + (quad * 4) * 1024 + j * 8;
#pragma unroll
        for (int r = 0; r < 4; ++r) {
          bf16x4 o;
#pragma unroll
          for (int q = 0; q < 4; ++q) o[q] = (short)f2bf(acc[q][r] + bs[q]);
          *(bf16x4*)(base + r * 1024) = o;
        }
      }
    } else {
      // y loads: relaxed agent atomics (IF$-coherent path), all issued first
      U8 af[4][4];
#pragma unroll
      for (int mt = 0; mt < 4; ++mt) {
        const unsigned short* ap = yin + ((size_t)(bg0 + mt) * TT + t0 + l15) * HH + quad * 8;
#pragma unroll
        for (int kc = 0; kc < 4; ++kc) {
          af[mt][kc].q[0] = yload8(ap + kc * 32);
          af[mt][kc].q[1] = yload8(ap + kc * 32 + 4);
        }
      }
#pragma unroll
      for (int mt = 0; mt < 4; ++mt) {
        f32x4 acc[4];
#pragma unroll
        for (int q = 0; q < 4; ++q) acc[q] = __builtin_amdgcn_mfma_f32_16x16x32_bf16(af[mt][0].v, bwi[q][0], z4, 0, 0, 0);
#pragma unroll
        for (int kc = 1; kc < 4; ++kc)
#pragma unroll
          for (int q = 0; q < 4; ++q) acc[q] = __builtin_amdgcn_mfma_f32_16x16x32_bf16(af[mt][kc].v, bwi[q][kc], acc[q], 0, 0, 0);
        char* base = xqls + mt * BSTR + (quad * 4) * 1024 + j * 8;
#pragma unroll
        for (int r = 0; r < 4; ++r) {
          bf16x4 o;
#pragma unroll
          for (int q = 0; q < 4; ++q) o[q] = (short)f2bf(acc[q][r] + bs[q]);
          *(bf16x4*)(base + r * 1024) = o;
        }
      }
    }
    bar_lds();

    // ---- CH recurrence steps ----
#pragma unroll
    for (int u = 0; u < CH; ++u) {
      int t = t0 + u;
      char* cur = hA + ((u & 1) << 10);          // CH even -> u&1 == t&1
      char* nxt = hA + (((u + 1) & 1) << 10);

      bf16x8 a0 = *(const bf16x8*)(cur + off_r);
      bf16x8 a1 = *(const bf16x8*)(cur + 256 + off_r);
      bf16x8 a2 = *(const bf16x8*)(cur + 512 + off_r);
      bf16x8 a3 = *(const bf16x8*)(cur + 768 + off_r);
      bf16x4 xq4 = *(const bf16x4*)(xqls + quad * BSTR + u * 1024 + j * 8);

      f32x4 c01[4], c23[4];
#pragma unroll
      for (int q = 0; q < 4; ++q) c01[q] = __builtin_amdgcn_mfma_f32_16x16x32_bf16(a0, bwh[q][0], z4, 0, 0, 0);
#pragma unroll
      for (int q = 0; q < 4; ++q) c23[q] = __builtin_amdgcn_mfma_f32_16x16x32_bf16(a2, bwh[q][2], z4, 0, 0, 0);
#pragma unroll
      for (int q = 0; q < 4; ++q) c01[q] = __builtin_amdgcn_mfma_f32_16x16x32_bf16(a1, bwh[q][1], c01[q], 0, 0, 0);
#pragma unroll
      for (int q = 0; q < 4; ++q) c23[q] = __builtin_amdgcn_mfma_f32_16x16x32_bf16(a3, bwh[q][3], c23[q], 0, 0, 0);

      if (layer == 2 && t > 0 && tid < 128) {
        bf16x4 hv4 = *(const bf16x4*)(cur + prd_off);
        float s = bf2f((unsigned short)hv4[0]) * wv[0] + bf2f((unsigned short)hv4[1]) * wv[1]
                + bf2f((unsigned short)hv4[2]) * wv[2] + bf2f((unsigned short)hv4[3]) * wv[3];
#pragma unroll
        for (int off = 16; off > 0; off >>= 1) s += __shfl_xor(s, off, 32);
        if ((tid & 31) == 0) outp[(size_t)(bg0 + pbl) * TT + (t - 1)] = fmaxf(s + ob, 0.f);
      }

      float gi = fsig(c01[0][0] + c23[0][0] + bf2f((unsigned short)xq4[0]));
      float gf = fsig(c01[1][0] + c23[1][0] + bf2f((unsigned short)xq4[1]));
      float gg = ftanh(c01[2][0] + c23[2][0] + bf2f((unsigned short)xq4[2]));
      float go = fsig(c01[3][0] + c23[3][0] + bf2f((unsigned short)xq4[3]));
      cc = gf * cc + gi * gg;
      hv = go * ftanh(cc);
      unsigned short hb = f2bf(hv);
      *(unsigned short*)(nxt + off_w) = hb;

      if (layer < 2) {
        // pack (j, j+1) and store as one relaxed agent-scope uint -> IF$
        int hx = __shfl_xor((int)(unsigned)hb, 1);
        if (!(l15 & 1)) {
          unsigned w = ((unsigned)hb & 0xFFFFu) | ((unsigned)hx << 16);
          __hip_atomic_store((unsigned*)(yo + (size_t)t * HH), w,
                             __ATOMIC_RELAXED, __HIP_MEMORY_SCOPE_AGENT);
        }
      }
      bar_lds();
    }

    // ---- producer: drain y stores (vmcnt only), publish chunk ----
    if (layer < 2) {
      asm volatile("s_waitcnt vmcnt(0)" ::: "memory");
      __syncthreads();
      if (tid == 0)
        __hip_atomic_store(flags + layer * NG + g, ck + 1,
                           __ATOMIC_RELAXED, __HIP_MEMORY_SCOPE_AGENT);
    }
  }

  float* hNl = hN + (size_t)layer * BATCH * HH;
  float* cNl = cN + (size_t)layer * BATCH * HH;
  hNl[(size_t)gb * HH + j] = hv;
  cNl[(size_t)gb * HH + j] = cc;

  if (layer == 2 && tid < 128) {   // h_1023 at parity 0
    bf16x4 hv4 = *(const bf16x4*)(hA + prd_off);
    float s = bf2f((unsigned short)hv4[0]) * wv[0] + bf2f((unsigned short)hv4[1]) * wv[1]
            + bf2f((unsigned short)hv4[2]) * wv[2] + bf2f((unsigned short)hv4[3]) * wv[3];
#pragma unroll
    for (int off = 16; off > 0; off >>= 1) s += __shfl_xor(s, off, 32);
    if ((tid & 31) == 0) outp[(size_t)(bg0 + pbl) * TT + (TT - 1)] = fmaxf(s + ob, 0.f);
  }
}

// ---------------- launch ----------------
extern "C" void kernel_launch(void* const* d_in, const int* in_sizes, int n_in,
                              void* d_out, int out_size, void* d_ws, size_t ws_size,
                              hipStream_t stream) {
  const float* x  = (const float*)d_in[0];
  const float* h0 = (const float*)d_in[1];
  const float* c0 = (const float*)d_in[2];
  const float* Wih[3] = {(const float*)d_in[3], (const float*)d_in[7],  (const float*)d_in[11]};
  const float* Whh[3] = {(const float*)d_in[4], (const float*)d_in[8],  (const float*)d_in[12]};
  const float* bih[3] = {(const float*)d_in[5], (const float*)d_in[9],  (const float*)d_in[13]};
  const float* bhh[3] = {(const float*)d_in[6], (const float*)d_in[10], (const float*)d_in[14]};
  const float* Wout = (const float*)d_in[15];
  const float* bout = (const float*)d_in[16];

  float* outp = (float*)d_out;                 // [B][T]
  float* hN = outp + BATCH * TT;               // [L][B][H]
  float* cN = hN + 3 * BATCH * HH;

  char* ws = (char*)d_ws;
  int* flags = (int*)ws;                                            // 64 ints
  unsigned short* y0 = (unsigned short*)(ws + 4096);                // 32 MB
  unsigned short* y1 = (unsigned short*)(ws + 4096 + (size_t)BATCH * TT * HH * 2);

  init_flags<<<1, 64, 0, stream>>>(flags);
  lstm_fused<<<3 * NG, 512, 0, stream>>>(
      x, h0, c0,
      Wih[0], Whh[0], bih[0], bhh[0],
      Wih[1], Whh[1], bih[1], bhh[1],
      Wih[2], Whh[2], bih[2], bhh[2],
      Wout, bout, y0, y1, outp, hN, cN, flags);
}

// Round 2
// 1593.395 us; speedup vs baseline: 1.0738x; 1.0667x over previous
//
#include <hip/hip_runtime.h>

// LSTM B=128,T=1024,H=128,D=64,L=3 — fused, layer-pipelined, R8.
// R8 change: move ALL per-step side-traffic off the recurrence critical path.
//  - Per-step y export (layers 0/1) was shfl_xor (ds_swizzle) + agent atomic
//    store INSIDE the step, drained by bar_lds's lgkmcnt(0). Now: one extra
//    ds_write_b16 to a per-chunk LDS stage buffer yst[CH][NB][128] (+32B pad
//    per batch -> conflict-free), bulk 8B agent stores at chunk end.
//  - Layer-2 projection was LDS read + serial 5-level shfl chain + global
//    store EVERY step in waves 0-1 (barrier makes all 8 waves pay). Now:
//    chunk-end phase, 64 outputs x 128-dot, 8 lanes/output + 3-level shfl.
//  - Step body is now identical for all layers (no divergent branches):
//    ds_read h/xq -> 16 MFMA -> gates -> 2x ds_write_b16 -> bar_lds.
// R6/R7 base: 96 WGs = 3 layers x 32 groups (NB=4, WG=512), relaxed
// agent-scope y exchange via IF$ ordered by vmcnt(0)+flag, CH=16,
// compressed 1KB h dbuf, lgkm-only barrier, Whh+Wih B-frags in VGPRs.

#define BATCH 128
#define TT    1024
#define HH    128
#define DD    64
#define NB    4
#define CH    16                // chunk steps
#define NG    32                // batch groups per layer
#define BSTR  (CH * 1024 + 8)   // xg LDS bytes per batch
#define YSTR  (CH * 256 + 32)   // y-stage LDS bytes per batch (+32 pad: conflict-free)

typedef __attribute__((ext_vector_type(4))) float f32x4;
typedef __attribute__((ext_vector_type(8))) short bf16x8;
typedef __attribute__((ext_vector_type(4))) short bf16x4;

union U8 { unsigned long long q[2]; bf16x8 v; };

__device__ inline unsigned short f2bf(float f) {           // RNE
  unsigned u = __builtin_bit_cast(unsigned, f);
  u += 0x7FFFu + ((u >> 16) & 1u);
  return (unsigned short)(u >> 16);
}
__device__ inline float bf2f(unsigned short s) {
  return __builtin_bit_cast(float, (unsigned)s << 16);
}
__device__ inline float fsig(float x) {
  return __builtin_amdgcn_rcpf(1.f + __builtin_amdgcn_exp2f(-1.442695041f * x));
}
__device__ inline float ftanh(float x) {
  return 2.f * __builtin_amdgcn_rcpf(1.f + __builtin_amdgcn_exp2f(-2.885390082f * x)) - 1.f;
}
__device__ inline bf16x8 pack8(f32x4 a, f32x4 b) {
  bf16x8 r;
  r[0]=(short)f2bf(a[0]); r[1]=(short)f2bf(a[1]); r[2]=(short)f2bf(a[2]); r[3]=(short)f2bf(a[3]);
  r[4]=(short)f2bf(b[0]); r[5]=(short)f2bf(b[1]); r[6]=(short)f2bf(b[2]); r[7]=(short)f2bf(b[3]);
  return r;
}
// LDS-only barrier: does NOT drain vmcnt.
__device__ inline void bar_lds() {
  asm volatile("s_waitcnt lgkmcnt(0)\n\ts_barrier" ::: "memory");
}
__device__ inline unsigned long long yload8(const unsigned short* p) {
  return __hip_atomic_load((unsigned long long*)p, __ATOMIC_RELAXED, __HIP_MEMORY_SCOPE_AGENT);
}
__device__ inline void ystore8(unsigned short* p, unsigned long long v) {
  __hip_atomic_store((unsigned long long*)p, v, __ATOMIC_RELAXED, __HIP_MEMORY_SCOPE_AGENT);
}

__global__ void init_flags(int* f) { if (threadIdx.x < 64) f[threadIdx.x] = 0; }

__global__ __launch_bounds__(512) void lstm_fused(
    const float* __restrict__ x,
    const float* __restrict__ h0, const float* __restrict__ c0,
    const float* __restrict__ Wih0, const float* __restrict__ Whh0,
    const float* __restrict__ bih0, const float* __restrict__ bhh0,
    const float* __restrict__ Wih1, const float* __restrict__ Whh1,
    const float* __restrict__ bih1, const float* __restrict__ bhh1,
    const float* __restrict__ Wih2, const float* __restrict__ Whh2,
    const float* __restrict__ bih2, const float* __restrict__ bhh2,
    const float* __restrict__ Wout, const float* __restrict__ boutp,
    unsigned short* __restrict__ y0, unsigned short* __restrict__ y1,
    float* __restrict__ outp, float* __restrict__ hN, float* __restrict__ cN,
    int* __restrict__ flags)
{
  __shared__ __align__(16) char xqls[NB * BSTR];   // xg chunk [b][t][j][gate]
  __shared__ __align__(16) char hA[2 * 1024];      // h dbuf, compressed A-order
  __shared__ __align__(16) char yst[NB * YSTR];    // per-chunk h stage [b][u][j]

  const int tid = threadIdx.x, wave = tid >> 6, lane = tid & 63;
  const int quad = lane >> 4, l15 = lane & 15;
  const int layer = blockIdx.x / NG, g = blockIdx.x % NG;
  const int bg0 = g * NB;
  const int gb = bg0 + quad;
  const int j = wave * 16 + l15;

  const float *Wih, *Whh, *bih, *bhh;
  const unsigned short* yin = nullptr;
  unsigned short* yout = nullptr;
  if (layer == 0)      { Wih = Wih0; Whh = Whh0; bih = bih0; bhh = bhh0; yout = y0; }
  else if (layer == 1) { Wih = Wih1; Whh = Whh1; bih = bih1; bhh = bhh1; yin = y0; yout = y1; }
  else                 { Wih = Wih2; Whh = Whh2; bih = bih2; bhh = bhh2; yin = y1; }
  const int Kin = (layer == 0) ? DD : HH;

  // Whh B-frags: tile n = q*128 + j, k = quad*8 + kc*32 + e
  bf16x8 bwh[4][4];
#pragma unroll
  for (int q = 0; q < 4; ++q)
#pragma unroll
    for (int kc = 0; kc < 4; ++kc) {
      const float* p = Whh + (size_t)(q * 128 + j) * HH + quad * 8 + kc * 32;
      bwh[q][kc] = pack8(*(const f32x4*)p, *(const f32x4*)(p + 4));
    }
  // Wih B-frags (K = 64 or 128)
  bf16x8 bwi[4][4];
#pragma unroll
  for (int q = 0; q < 4; ++q)
    for (int kc = 0; kc < Kin / 32; ++kc) {
      const float* p = Wih + (size_t)(q * 128 + j) * Kin + quad * 8 + kc * 32;
      bwi[q][kc] = pack8(*(const f32x4*)p, *(const f32x4*)(p + 4));
    }
  float bs[4];
#pragma unroll
  for (int q = 0; q < 4; ++q) bs[q] = bih[q * 128 + j] + bhh[q * 128 + j];

  // compressed h layout: h[b][k] at byte
  //   (k>>5)*256 + (((k>>3)&3)*4 + b)*16 + (k&7)*2
  int off_w = (wave >> 1) * 256 + (((((wave & 1) << 1) | (l15 >> 3)) * 4) + quad) * 16 + (l15 & 7) * 2;
  int off_r = (quad * 4 + (l15 >> 2)) * 16;

  const float* h0l = h0 + (size_t)layer * BATCH * HH;
  const float* c0l = c0 + (size_t)layer * BATCH * HH;
  *(unsigned short*)(hA + off_w) = f2bf(h0l[(size_t)gb * HH + j]);
  float cc = c0l[(size_t)gb * HH + j];

  // projection weights (layer 2): Wout[lg*16 .. lg*16+15] per lane group
  f32x4 wvp0 = {0,0,0,0}, wvp1 = {0,0,0,0}, wvp2 = {0,0,0,0}, wvp3 = {0,0,0,0};
  float ob = 0.f;
  if (layer == 2) {
    const float* wp = Wout + (lane & 7) * 16;
    wvp0 = *(const f32x4*)(wp + 0);
    wvp1 = *(const f32x4*)(wp + 4);
    wvp2 = *(const f32x4*)(wp + 8);
    wvp3 = *(const f32x4*)(wp + 12);
    ob = boutp[0];
  }

  __syncthreads();

  const f32x4 z4 = {0.f, 0.f, 0.f, 0.f};
  float hv = 0.f;
  const int yst_w = quad * YSTR + j * 2;   // + u*256 per step

  for (int ck = 0; ck < TT / CH; ++ck) {
    int t0 = ck * CH;

    // ---- consumer: wait for producer chunk (acquire on flag only) ----
    if (layer > 0) {
      if (tid == 0) {
        while (__hip_atomic_load(flags + (layer - 1) * NG + g,
                                 __ATOMIC_ACQUIRE, __HIP_MEMORY_SCOPE_AGENT) <= ck)
          __builtin_amdgcn_s_sleep(1);
      }
      __syncthreads();
    }

    // ---- fused chunk GEMM: 4 M-tiles, tile mt = batch bg0+mt x 16 steps ----
    if (layer == 0) {
      bf16x8 af[4][2];
#pragma unroll
      for (int mt = 0; mt < 4; ++mt) {
        const float* ap = x + ((size_t)(bg0 + mt) * TT + t0 + l15) * DD + quad * 8;
        af[mt][0] = pack8(*(const f32x4*)ap, *(const f32x4*)(ap + 4));
        af[mt][1] = pack8(*(const f32x4*)(ap + 32), *(const f32x4*)(ap + 36));
      }
#pragma unroll
      for (int mt = 0; mt < 4; ++mt) {
        f32x4 acc[4];
#pragma unroll
        for (int q = 0; q < 4; ++q) acc[q] = __builtin_amdgcn_mfma_f32_16x16x32_bf16(af[mt][0], bwi[q][0], z4, 0, 0, 0);
#pragma unroll
        for (int q = 0; q < 4; ++q) acc[q] = __builtin_amdgcn_mfma_f32_16x16x32_bf16(af[mt][1], bwi[q][1], acc[q], 0, 0, 0);
        char* base = xqls + mt * BSTR + (quad * 4) * 1024 + j * 8;
#pragma unroll
        for (int r = 0; r < 4; ++r) {
          bf16x4 o;
#pragma unroll
          for (int q = 0; q < 4; ++q) o[q] = (short)f2bf(acc[q][r] + bs[q]);
          *(bf16x4*)(base + r * 1024) = o;
        }
      }
    } else {
      // y loads: relaxed agent atomics (IF$-coherent path), all issued first
      U8 af[4][4];
#pragma unroll
      for (int mt = 0; mt < 4; ++mt) {
        const unsigned short* ap = yin + ((size_t)(bg0 + mt) * TT + t0 + l15) * HH + quad * 8;
#pragma unroll
        for (int kc = 0; kc < 4; ++kc) {
          af[mt][kc].q[0] = yload8(ap + kc * 32);
          af[mt][kc].q[1] = yload8(ap + kc * 32 + 4);
        }
      }
#pragma unroll
      for (int mt = 0; mt < 4; ++mt) {
        f32x4 acc[4];
#pragma unroll
        for (int q = 0; q < 4; ++q) acc[q] = __builtin_amdgcn_mfma_f32_16x16x32_bf16(af[mt][0].v, bwi[q][0], z4, 0, 0, 0);
#pragma unroll
        for (int kc = 1; kc < 4; ++kc)
#pragma unroll
          for (int q = 0; q < 4; ++q) acc[q] = __builtin_amdgcn_mfma_f32_16x16x32_bf16(af[mt][kc].v, bwi[q][kc], acc[q], 0, 0, 0);
        char* base = xqls + mt * BSTR + (quad * 4) * 1024 + j * 8;
#pragma unroll
        for (int r = 0; r < 4; ++r) {
          bf16x4 o;
#pragma unroll
          for (int q = 0; q < 4; ++q) o[q] = (short)f2bf(acc[q][r] + bs[q]);
          *(bf16x4*)(base + r * 1024) = o;
        }
      }
    }
    bar_lds();

    // ---- CH recurrence steps (uniform body, no divergence) ----
#pragma unroll
    for (int u = 0; u < CH; ++u) {
      char* cur = hA + ((u & 1) << 10);          // CH even -> u&1 == t&1
      char* nxt = hA + (((u + 1) & 1) << 10);

      bf16x8 a0 = *(const bf16x8*)(cur + off_r);
      bf16x8 a1 = *(const bf16x8*)(cur + 256 + off_r);
      bf16x8 a2 = *(const bf16x8*)(cur + 512 + off_r);
      bf16x8 a3 = *(const bf16x8*)(cur + 768 + off_r);
      bf16x4 xq4 = *(const bf16x4*)(xqls + quad * BSTR + u * 1024 + j * 8);

      f32x4 c01[4], c23[4];
#pragma unroll
      for (int q = 0; q < 4; ++q) c01[q] = __builtin_amdgcn_mfma_f32_16x16x32_bf16(a0, bwh[q][0], z4, 0, 0, 0);
#pragma unroll
      for (int q = 0; q < 4; ++q) c23[q] = __builtin_amdgcn_mfma_f32_16x16x32_bf16(a2, bwh[q][2], z4, 0, 0, 0);
#pragma unroll
      for (int q = 0; q < 4; ++q) c01[q] = __builtin_amdgcn_mfma_f32_16x16x32_bf16(a1, bwh[q][1], c01[q], 0, 0, 0);
#pragma unroll
      for (int q = 0; q < 4; ++q) c23[q] = __builtin_amdgcn_mfma_f32_16x16x32_bf16(a3, bwh[q][3], c23[q], 0, 0, 0);

      float gi = fsig(c01[0][0] + c23[0][0] + bf2f((unsigned short)xq4[0]));
      float gf = fsig(c01[1][0] + c23[1][0] + bf2f((unsigned short)xq4[1]));
      float gg = ftanh(c01[2][0] + c23[2][0] + bf2f((unsigned short)xq4[2]));
      float go = fsig(c01[3][0] + c23[3][0] + bf2f((unsigned short)xq4[3]));
      cc = gf * cc + gi * gg;
      hv = go * ftanh(cc);
      unsigned short hb = f2bf(hv);
      *(unsigned short*)(nxt + off_w) = hb;                 // h exchange
      *(unsigned short*)(yst + yst_w + u * 256) = hb;       // y/proj stage
      bar_lds();
    }

    // ---- chunk epilogue ----
    if (layer < 2) {
      // bulk y export: 16 KB stage -> global via wide agent-scope stores
#pragma unroll
      for (int s = 0; s < 2; ++s) {
        int seg = tid + s * 512;
        int b = seg >> 8, u = (seg >> 4) & 15, part = seg & 15;
        U8 v; v.v = *(const bf16x8*)(yst + b * YSTR + u * 256 + part * 16);
        size_t di = ((size_t)(bg0 + b) * TT + t0 + u) * HH + part * 8;
        ystore8(yout + di, v.q[0]);
        ystore8(yout + di + 4, v.q[1]);
      }
      asm volatile("s_waitcnt vmcnt(0)" ::: "memory");
      __syncthreads();
      if (tid == 0)
        __hip_atomic_store(flags + layer * NG + g, ck + 1,
                           __ATOMIC_RELAXED, __HIP_MEMORY_SCOPE_AGENT);
    } else {
      // projection: 64 outputs (4 b x 16 u), 8 lanes per output
      int og = lane >> 3, lg = lane & 7;
      int o = wave * 8 + og;
      int b = o >> 4, u = o & 15;
      const char* sp = yst + b * YSTR + u * 256 + lg * 32;
      bf16x8 ha = *(const bf16x8*)sp;
      bf16x8 hbv = *(const bf16x8*)(sp + 16);
      float s = 0.f;
#pragma unroll
      for (int e = 0; e < 4; ++e) s += bf2f((unsigned short)ha[e]) * wvp0[e];
#pragma unroll
      for (int e = 0; e < 4; ++e) s += bf2f((unsigned short)ha[e + 4]) * wvp1[e];
#pragma unroll
      for (int e = 0; e < 4; ++e) s += bf2f((unsigned short)hbv[e]) * wvp2[e];
#pragma unroll
      for (int e = 0; e < 4; ++e) s += bf2f((unsigned short)hbv[e + 4]) * wvp3[e];
      s += __shfl_xor(s, 1);
      s += __shfl_xor(s, 2);
      s += __shfl_xor(s, 4);
      if (lg == 0) outp[(size_t)(bg0 + b) * TT + t0 + u] = fmaxf(s + ob, 0.f);
      // yst reads complete (lgkm) before next chunk's stage writes, which
      // happen after the consumer-wait __syncthreads + GEMM + bar_lds.
    }
  }

  float* hNl = hN + (size_t)layer * BATCH * HH;
  float* cNl = cN + (size_t)layer * BATCH * HH;
  hNl[(size_t)gb * HH + j] = hv;
  cNl[(size_t)gb * HH + j] = cc;
}

// ---------------- launch ----------------
extern "C" void kernel_launch(void* const* d_in, const int* in_sizes, int n_in,
                              void* d_out, int out_size, void* d_ws, size_t ws_size,
                              hipStream_t stream) {
  const float* x  = (const float*)d_in[0];
  const float* h0 = (const float*)d_in[1];
  const float* c0 = (const float*)d_in[2];
  const float* Wih[3] = {(const float*)d_in[3], (const float*)d_in[7],  (const float*)d_in[11]};
  const float* Whh[3] = {(const float*)d_in[4], (const float*)d_in[8],  (const float*)d_in[12]};
  const float* bih[3] = {(const float*)d_in[5], (const float*)d_in[9],  (const float*)d_in[13]};
  const float* bhh[3] = {(const float*)d_in[6], (const float*)d_in[10], (const float*)d_in[14]};
  const float* Wout = (const float*)d_in[15];
  const float* bout = (const float*)d_in[16];

  float* outp = (float*)d_out;                 // [B][T]
  float* hN = outp + BATCH * TT;               // [L][B][H]
  float* cN = hN + 3 * BATCH * HH;

  char* ws = (char*)d_ws;
  int* flags = (int*)ws;                                            // 64 ints
  unsigned short* y0 = (unsigned short*)(ws + 4096);                // 32 MB
  unsigned short* y1 = (unsigned short*)(ws + 4096 + (size_t)BATCH * TT * HH * 2);

  init_flags<<<1, 64, 0, stream>>>(flags);
  lstm_fused<<<3 * NG, 512, 0, stream>>>(
      x, h0, c0,
      Wih[0], Whh[0], bih[0], bhh[0],
      Wih[1], Whh[1], bih[1], bhh[1],
      Wih[2], Whh[2], bih[2], bhh[2],
      Wout, bout, y0, y1, outp, hN, cN, flags);
}

// Round 3
// 1369.433 us; speedup vs baseline: 1.2494x; 1.1635x over previous
//
#include <hip/hip_runtime.h>

// LSTM B=128,T=1024,H=128,D=64,L=3 — fused, layer-pipelined, R9.
// R9 change: the consumer GEMM's 32 per-lane __hip_atomic_load's were
// SERIALIZED by conservative atomic codegen (one vmcnt drain per load ->
// ~32 x 650cyc = ~10us/chunk, exactly the measured 9.4us gap between layer 0
// (14us/chunk, no atomic loads) and layers 1/2 (23.4us/chunk, the pacers).
// Now: one inline-asm block issues 16 global_load_dwordx4 with sc0 sc1
// (L1+L2 bypass -> IF$, preserving cross-XCD coherence vs the producer's
// agent-scope stores) and ONE s_waitcnt vmcnt(0) at the end. Same bytes,
// same coherence, batched latency.
// R8 base: per-chunk LDS y-stage (yst) + bulk chunk-end export / chunk-end
// projection; uniform step body. 96 WGs = 3 layers x 32 groups (NB=4,
// WG=512), relaxed agent-scope y exchange via IF$ ordered by vmcnt(0)+flag,
// CH=16, compressed 1KB h dbuf, lgkm-only barrier, Whh+Wih B-frags in VGPRs.

#define BATCH 128
#define TT    1024
#define HH    128
#define DD    64
#define NB    4
#define CH    16                // chunk steps
#define NG    32                // batch groups per layer
#define BSTR  (CH * 1024 + 8)   // xg LDS bytes per batch
#define YSTR  (CH * 256 + 32)   // y-stage LDS bytes per batch (+32 pad: conflict-free)

typedef __attribute__((ext_vector_type(4))) float f32x4;
typedef __attribute__((ext_vector_type(8))) short bf16x8;
typedef __attribute__((ext_vector_type(4))) short bf16x4;
typedef __attribute__((ext_vector_type(4))) unsigned u32x4;

union U8 { unsigned long long q[2]; bf16x8 v; };

__device__ inline unsigned short f2bf(float f) {           // RNE
  unsigned u = __builtin_bit_cast(unsigned, f);
  u += 0x7FFFu + ((u >> 16) & 1u);
  return (unsigned short)(u >> 16);
}
__device__ inline float bf2f(unsigned short s) {
  return __builtin_bit_cast(float, (unsigned)s << 16);
}
__device__ inline float fsig(float x) {
  return __builtin_amdgcn_rcpf(1.f + __builtin_amdgcn_exp2f(-1.442695041f * x));
}
__device__ inline float ftanh(float x) {
  return 2.f * __builtin_amdgcn_rcpf(1.f + __builtin_amdgcn_exp2f(-2.885390082f * x)) - 1.f;
}
__device__ inline bf16x8 pack8(f32x4 a, f32x4 b) {
  bf16x8 r;
  r[0]=(short)f2bf(a[0]); r[1]=(short)f2bf(a[1]); r[2]=(short)f2bf(a[2]); r[3]=(short)f2bf(a[3]);
  r[4]=(short)f2bf(b[0]); r[5]=(short)f2bf(b[1]); r[6]=(short)f2bf(b[2]); r[7]=(short)f2bf(b[3]);
  return r;
}
// LDS-only barrier: does NOT drain vmcnt.
__device__ inline void bar_lds() {
  asm volatile("s_waitcnt lgkmcnt(0)\n\ts_barrier" ::: "memory");
}
__device__ inline void ystore8(unsigned short* p, unsigned long long v) {
  __hip_atomic_store((unsigned long long*)p, v, __ATOMIC_RELAXED, __HIP_MEMORY_SCOPE_AGENT);
}

__global__ void init_flags(int* f) { if (threadIdx.x < 64) f[threadIdx.x] = 0; }

__global__ __launch_bounds__(512) void lstm_fused(
    const float* __restrict__ x,
    const float* __restrict__ h0, const float* __restrict__ c0,
    const float* __restrict__ Wih0, const float* __restrict__ Whh0,
    const float* __restrict__ bih0, const float* __restrict__ bhh0,
    const float* __restrict__ Wih1, const float* __restrict__ Whh1,
    const float* __restrict__ bih1, const float* __restrict__ bhh1,
    const float* __restrict__ Wih2, const float* __restrict__ Whh2,
    const float* __restrict__ bih2, const float* __restrict__ bhh2,
    const float* __restrict__ Wout, const float* __restrict__ boutp,
    unsigned short* __restrict__ y0, unsigned short* __restrict__ y1,
    float* __restrict__ outp, float* __restrict__ hN, float* __restrict__ cN,
    int* __restrict__ flags)
{
  __shared__ __align__(16) char xqls[NB * BSTR];   // xg chunk [b][t][j][gate]
  __shared__ __align__(16) char hA[2 * 1024];      // h dbuf, compressed A-order
  __shared__ __align__(16) char yst[NB * YSTR];    // per-chunk h stage [b][u][j]

  const int tid = threadIdx.x, wave = tid >> 6, lane = tid & 63;
  const int quad = lane >> 4, l15 = lane & 15;
  const int layer = blockIdx.x / NG, g = blockIdx.x % NG;
  const int bg0 = g * NB;
  const int gb = bg0 + quad;
  const int j = wave * 16 + l15;

  const float *Wih, *Whh, *bih, *bhh;
  const unsigned short* yin = nullptr;
  unsigned short* yout = nullptr;
  if (layer == 0)      { Wih = Wih0; Whh = Whh0; bih = bih0; bhh = bhh0; yout = y0; }
  else if (layer == 1) { Wih = Wih1; Whh = Whh1; bih = bih1; bhh = bhh1; yin = y0; yout = y1; }
  else                 { Wih = Wih2; Whh = Whh2; bih = bih2; bhh = bhh2; yin = y1; }
  const int Kin = (layer == 0) ? DD : HH;

  // Whh B-frags: tile n = q*128 + j, k = quad*8 + kc*32 + e
  bf16x8 bwh[4][4];
#pragma unroll
  for (int q = 0; q < 4; ++q)
#pragma unroll
    for (int kc = 0; kc < 4; ++kc) {
      const float* p = Whh + (size_t)(q * 128 + j) * HH + quad * 8 + kc * 32;
      bwh[q][kc] = pack8(*(const f32x4*)p, *(const f32x4*)(p + 4));
    }
  // Wih B-frags (K = 64 or 128)
  bf16x8 bwi[4][4];
#pragma unroll
  for (int q = 0; q < 4; ++q)
    for (int kc = 0; kc < Kin / 32; ++kc) {
      const float* p = Wih + (size_t)(q * 128 + j) * Kin + quad * 8 + kc * 32;
      bwi[q][kc] = pack8(*(const f32x4*)p, *(const f32x4*)(p + 4));
    }
  float bs[4];
#pragma unroll
  for (int q = 0; q < 4; ++q) bs[q] = bih[q * 128 + j] + bhh[q * 128 + j];

  // compressed h layout: h[b][k] at byte
  //   (k>>5)*256 + (((k>>3)&3)*4 + b)*16 + (k&7)*2
  int off_w = (wave >> 1) * 256 + (((((wave & 1) << 1) | (l15 >> 3)) * 4) + quad) * 16 + (l15 & 7) * 2;
  int off_r = (quad * 4 + (l15 >> 2)) * 16;

  const float* h0l = h0 + (size_t)layer * BATCH * HH;
  const float* c0l = c0 + (size_t)layer * BATCH * HH;
  *(unsigned short*)(hA + off_w) = f2bf(h0l[(size_t)gb * HH + j]);
  float cc = c0l[(size_t)gb * HH + j];

  // projection weights (layer 2): Wout[lg*16 .. lg*16+15] per lane group
  f32x4 wvp0 = {0,0,0,0}, wvp1 = {0,0,0,0}, wvp2 = {0,0,0,0}, wvp3 = {0,0,0,0};
  float ob = 0.f;
  if (layer == 2) {
    const float* wp = Wout + (lane & 7) * 16;
    wvp0 = *(const f32x4*)(wp + 0);
    wvp1 = *(const f32x4*)(wp + 4);
    wvp2 = *(const f32x4*)(wp + 8);
    wvp3 = *(const f32x4*)(wp + 12);
    ob = boutp[0];
  }

  __syncthreads();

  const f32x4 z4 = {0.f, 0.f, 0.f, 0.f};
  float hv = 0.f;
  const int yst_w = quad * YSTR + j * 2;   // + u*256 per step

  for (int ck = 0; ck < TT / CH; ++ck) {
    int t0 = ck * CH;

    // ---- consumer: wait for producer chunk (acquire on flag only) ----
    if (layer > 0) {
      if (tid == 0) {
        while (__hip_atomic_load(flags + (layer - 1) * NG + g,
                                 __ATOMIC_ACQUIRE, __HIP_MEMORY_SCOPE_AGENT) <= ck)
          __builtin_amdgcn_s_sleep(1);
      }
      __syncthreads();
    }

    // ---- fused chunk GEMM: 4 M-tiles, tile mt = batch bg0+mt x 16 steps ----
    if (layer == 0) {
      bf16x8 af[4][2];
#pragma unroll
      for (int mt = 0; mt < 4; ++mt) {
        const float* ap = x + ((size_t)(bg0 + mt) * TT + t0 + l15) * DD + quad * 8;
        af[mt][0] = pack8(*(const f32x4*)ap, *(const f32x4*)(ap + 4));
        af[mt][1] = pack8(*(const f32x4*)(ap + 32), *(const f32x4*)(ap + 36));
      }
#pragma unroll
      for (int mt = 0; mt < 4; ++mt) {
        f32x4 acc[4];
#pragma unroll
        for (int q = 0; q < 4; ++q) acc[q] = __builtin_amdgcn_mfma_f32_16x16x32_bf16(af[mt][0], bwi[q][0], z4, 0, 0, 0);
#pragma unroll
        for (int q = 0; q < 4; ++q) acc[q] = __builtin_amdgcn_mfma_f32_16x16x32_bf16(af[mt][1], bwi[q][1], acc[q], 0, 0, 0);
        char* base = xqls + mt * BSTR + (quad * 4) * 1024 + j * 8;
#pragma unroll
        for (int r = 0; r < 4; ++r) {
          bf16x4 o;
#pragma unroll
          for (int q = 0; q < 4; ++q) o[q] = (short)f2bf(acc[q][r] + bs[q]);
          *(bf16x4*)(base + r * 1024) = o;
        }
      }
    } else {
      // y loads: 16x global_load_dwordx4 sc0 sc1 (L1+L2 bypass -> IF$),
      // batched in ONE asm block with a single vmcnt(0) drain at the end.
      // (The previous per-lane __hip_atomic_load path was serialized by
      // codegen: one vmcnt drain per load = ~10us/chunk.)
      u32x4 yq[4][4];
      const unsigned short* a0p = yin + ((size_t)(bg0 + 0) * TT + t0 + l15) * HH + quad * 8;
      const unsigned short* a1p = yin + ((size_t)(bg0 + 1) * TT + t0 + l15) * HH + quad * 8;
      const unsigned short* a2p = yin + ((size_t)(bg0 + 2) * TT + t0 + l15) * HH + quad * 8;
      const unsigned short* a3p = yin + ((size_t)(bg0 + 3) * TT + t0 + l15) * HH + quad * 8;
      asm volatile(
        "global_load_dwordx4 %[q00], %[a0], off sc0 sc1\n\t"
        "global_load_dwordx4 %[q01], %[a0], off offset:64 sc0 sc1\n\t"
        "global_load_dwordx4 %[q02], %[a0], off offset:128 sc0 sc1\n\t"
        "global_load_dwordx4 %[q03], %[a0], off offset:192 sc0 sc1\n\t"
        "global_load_dwordx4 %[q10], %[a1], off sc0 sc1\n\t"
        "global_load_dwordx4 %[q11], %[a1], off offset:64 sc0 sc1\n\t"
        "global_load_dwordx4 %[q12], %[a1], off offset:128 sc0 sc1\n\t"
        "global_load_dwordx4 %[q13], %[a1], off offset:192 sc0 sc1\n\t"
        "global_load_dwordx4 %[q20], %[a2], off sc0 sc1\n\t"
        "global_load_dwordx4 %[q21], %[a2], off offset:64 sc0 sc1\n\t"
        "global_load_dwordx4 %[q22], %[a2], off offset:128 sc0 sc1\n\t"
        "global_load_dwordx4 %[q23], %[a2], off offset:192 sc0 sc1\n\t"
        "global_load_dwordx4 %[q30], %[a3], off sc0 sc1\n\t"
        "global_load_dwordx4 %[q31], %[a3], off offset:64 sc0 sc1\n\t"
        "global_load_dwordx4 %[q32], %[a3], off offset:128 sc0 sc1\n\t"
        "global_load_dwordx4 %[q33], %[a3], off offset:192 sc0 sc1\n\t"
        "s_waitcnt vmcnt(0)"
        : [q00]"=v"(yq[0][0]), [q01]"=v"(yq[0][1]), [q02]"=v"(yq[0][2]), [q03]"=v"(yq[0][3]),
          [q10]"=v"(yq[1][0]), [q11]"=v"(yq[1][1]), [q12]"=v"(yq[1][2]), [q13]"=v"(yq[1][3]),
          [q20]"=v"(yq[2][0]), [q21]"=v"(yq[2][1]), [q22]"=v"(yq[2][2]), [q23]"=v"(yq[2][3]),
          [q30]"=v"(yq[3][0]), [q31]"=v"(yq[3][1]), [q32]"=v"(yq[3][2]), [q33]"=v"(yq[3][3])
        : [a0]"v"(a0p), [a1]"v"(a1p), [a2]"v"(a2p), [a3]"v"(a3p)
        : "memory");
#pragma unroll
      for (int mt = 0; mt < 4; ++mt) {
        f32x4 acc[4];
#pragma unroll
        for (int q = 0; q < 4; ++q) acc[q] = __builtin_amdgcn_mfma_f32_16x16x32_bf16(__builtin_bit_cast(bf16x8, yq[mt][0]), bwi[q][0], z4, 0, 0, 0);
#pragma unroll
        for (int kc = 1; kc < 4; ++kc)
#pragma unroll
          for (int q = 0; q < 4; ++q) acc[q] = __builtin_amdgcn_mfma_f32_16x16x32_bf16(__builtin_bit_cast(bf16x8, yq[mt][kc]), bwi[q][kc], acc[q], 0, 0, 0);
        char* base = xqls + mt * BSTR + (quad * 4) * 1024 + j * 8;
#pragma unroll
        for (int r = 0; r < 4; ++r) {
          bf16x4 o;
#pragma unroll
          for (int q = 0; q < 4; ++q) o[q] = (short)f2bf(acc[q][r] + bs[q]);
          *(bf16x4*)(base + r * 1024) = o;
        }
      }
    }
    bar_lds();

    // ---- CH recurrence steps (uniform body, no divergence) ----
#pragma unroll
    for (int u = 0; u < CH; ++u) {
      char* cur = hA + ((u & 1) << 10);          // CH even -> u&1 == t&1
      char* nxt = hA + (((u + 1) & 1) << 10);

      bf16x8 a0 = *(const bf16x8*)(cur + off_r);
      bf16x8 a1 = *(const bf16x8*)(cur + 256 + off_r);
      bf16x8 a2 = *(const bf16x8*)(cur + 512 + off_r);
      bf16x8 a3 = *(const bf16x8*)(cur + 768 + off_r);
      bf16x4 xq4 = *(const bf16x4*)(xqls + quad * BSTR + u * 1024 + j * 8);

      f32x4 c01[4], c23[4];
#pragma unroll
      for (int q = 0; q < 4; ++q) c01[q] = __builtin_amdgcn_mfma_f32_16x16x32_bf16(a0, bwh[q][0], z4, 0, 0, 0);
#pragma unroll
      for (int q = 0; q < 4; ++q) c23[q] = __builtin_amdgcn_mfma_f32_16x16x32_bf16(a2, bwh[q][2], z4, 0, 0, 0);
#pragma unroll
      for (int q = 0; q < 4; ++q) c01[q] = __builtin_amdgcn_mfma_f32_16x16x32_bf16(a1, bwh[q][1], c01[q], 0, 0, 0);
#pragma unroll
      for (int q = 0; q < 4; ++q) c23[q] = __builtin_amdgcn_mfma_f32_16x16x32_bf16(a3, bwh[q][3], c23[q], 0, 0, 0);

      float gi = fsig(c01[0][0] + c23[0][0] + bf2f((unsigned short)xq4[0]));
      float gf = fsig(c01[1][0] + c23[1][0] + bf2f((unsigned short)xq4[1]));
      float gg = ftanh(c01[2][0] + c23[2][0] + bf2f((unsigned short)xq4[2]));
      float go = fsig(c01[3][0] + c23[3][0] + bf2f((unsigned short)xq4[3]));
      cc = gf * cc + gi * gg;
      hv = go * ftanh(cc);
      unsigned short hb = f2bf(hv);
      *(unsigned short*)(nxt + off_w) = hb;                 // h exchange
      *(unsigned short*)(yst + yst_w + u * 256) = hb;       // y/proj stage
      bar_lds();
    }

    // ---- chunk epilogue ----
    if (layer < 2) {
      // bulk y export: 16 KB stage -> global via wide agent-scope stores
#pragma unroll
      for (int s = 0; s < 2; ++s) {
        int seg = tid + s * 512;
        int b = seg >> 8, u = (seg >> 4) & 15, part = seg & 15;
        U8 v; v.v = *(const bf16x8*)(yst + b * YSTR + u * 256 + part * 16);
        size_t di = ((size_t)(bg0 + b) * TT + t0 + u) * HH + part * 8;
        ystore8(yout + di, v.q[0]);
        ystore8(yout + di + 4, v.q[1]);
      }
      asm volatile("s_waitcnt vmcnt(0)" ::: "memory");
      __syncthreads();
      if (tid == 0)
        __hip_atomic_store(flags + layer * NG + g, ck + 1,
                           __ATOMIC_RELAXED, __HIP_MEMORY_SCOPE_AGENT);
    } else {
      // projection: 64 outputs (4 b x 16 u), 8 lanes per output
      int og = lane >> 3, lg = lane & 7;
      int o = wave * 8 + og;
      int b = o >> 4, u = o & 15;
      const char* sp = yst + b * YSTR + u * 256 + lg * 32;
      bf16x8 ha = *(const bf16x8*)sp;
      bf16x8 hbv = *(const bf16x8*)(sp + 16);
      float s = 0.f;
#pragma unroll
      for (int e = 0; e < 4; ++e) s += bf2f((unsigned short)ha[e]) * wvp0[e];
#pragma unroll
      for (int e = 0; e < 4; ++e) s += bf2f((unsigned short)ha[e + 4]) * wvp1[e];
#pragma unroll
      for (int e = 0; e < 4; ++e) s += bf2f((unsigned short)hbv[e]) * wvp2[e];
#pragma unroll
      for (int e = 0; e < 4; ++e) s += bf2f((unsigned short)hbv[e + 4]) * wvp3[e];
      s += __shfl_xor(s, 1);
      s += __shfl_xor(s, 2);
      s += __shfl_xor(s, 4);
      if (lg == 0) outp[(size_t)(bg0 + b) * TT + t0 + u] = fmaxf(s + ob, 0.f);
      // yst reads complete (lgkm) before next chunk's stage writes, which
      // happen after the consumer-wait __syncthreads + GEMM + bar_lds.
    }
  }

  float* hNl = hN + (size_t)layer * BATCH * HH;
  float* cNl = cN + (size_t)layer * BATCH * HH;
  hNl[(size_t)gb * HH + j] = hv;
  cNl[(size_t)gb * HH + j] = cc;
}

// ---------------- launch ----------------
extern "C" void kernel_launch(void* const* d_in, const int* in_sizes, int n_in,
                              void* d_out, int out_size, void* d_ws, size_t ws_size,
                              hipStream_t stream) {
  const float* x  = (const float*)d_in[0];
  const float* h0 = (const float*)d_in[1];
  const float* c0 = (const float*)d_in[2];
  const float* Wih[3] = {(const float*)d_in[3], (const float*)d_in[7],  (const float*)d_in[11]};
  const float* Whh[3] = {(const float*)d_in[4], (const float*)d_in[8],  (const float*)d_in[12]};
  const float* bih[3] = {(const float*)d_in[5], (const float*)d_in[9],  (const float*)d_in[13]};
  const float* bhh[3] = {(const float*)d_in[6], (const float*)d_in[10], (const float*)d_in[14]};
  const float* Wout = (const float*)d_in[15];
  const float* bout = (const float*)d_in[16];

  float* outp = (float*)d_out;                 // [B][T]
  float* hN = outp + BATCH * TT;               // [L][B][H]
  float* cN = hN + 3 * BATCH * HH;

  char* ws = (char*)d_ws;
  int* flags = (int*)ws;                                            // 64 ints
  unsigned short* y0 = (unsigned short*)(ws + 4096);                // 32 MB
  unsigned short* y1 = (unsigned short*)(ws + 4096 + (size_t)BATCH * TT * HH * 2);

  init_flags<<<1, 64, 0, stream>>>(flags);
  lstm_fused<<<3 * NG, 512, 0, stream>>>(
      x, h0, c0,
      Wih[0], Whh[0], bih[0], bhh[0],
      Wih[1], Whh[1], bih[1], bhh[1],
      Wih[2], Whh[2], bih[2], bhh[2],
      Wout, bout, y0, y1, outp, hN, cN, flags);
}

// Round 5
// 1120.944 us; speedup vs baseline: 1.5264x; 1.2217x over previous
//
#include <hip/hip_runtime.h>

// LSTM B=128,T=1024,H=128,D=64,L=3 — fused, layer-pipelined, R11.
// R11 change: fix the R10 correctness race (rule-#18 hazard). R10's prefetch
// read the producer flag via inline-asm load at step 0 and waited with a
// SEPARATE "s_waitcnt vmcnt(0)" asm at step 2 — but the register-only
// compare (__any(fvp > ck+1)) could be scheduled BEFORE the waitcnt
// ("memory" clobber only orders memory ops; the compiler's waitcnt pass
// can't see inline-asm loads; HW does not interlock VGPR reads against
// in-flight loads). Stale/garbage fvp -> spurious rdy=1 -> prefetch of
// unpublished y data (absmax 0.134). Fix: tie fvp THROUGH the waitcnt asm
// ("+v" redefinition = true data dependence) + sched_barrier(0) fences
// (same after the step-10 prefetch drain, defensive).
// R10 base: chunk-handoff off the critical path — flag poll + A-tile loads
// for chunk ck+1 issued at steps 0-3, drained+staged into a 16KB swizzled
// LDS stage at step 10, chunk top skips poll/syncthreads/load-wait when
// prefetched; IF$ traffic /8 (A-tile loaded once per WG, not per wave).
// R9 base: batched sc0sc1 y-loads, chunk-end bulk y export + projection,
// uniform step body, compressed 1KB h dbuf, lgkm-only barrier, Whh+Wih
// B-frags in registers, 96 WGs = 3 layers x 32 groups, CH=16.

#define BATCH 128
#define TT    1024
#define HH    128
#define DD    64
#define NB    4
#define CH    16                // chunk steps
#define NG    32                // batch groups per layer
#define NCK   (TT / CH)
#define BSTR  (CH * 1024 + 8)   // xg LDS bytes per batch
#define YSTR  (CH * 256 + 32)   // y-stage LDS bytes per batch (+32 pad)

typedef __attribute__((ext_vector_type(4))) float f32x4;
typedef __attribute__((ext_vector_type(8))) short bf16x8;
typedef __attribute__((ext_vector_type(4))) short bf16x4;
typedef __attribute__((ext_vector_type(4))) unsigned u32x4;

union U8 { unsigned long long q[2]; bf16x8 v; };

__device__ inline unsigned short f2bf(float f) {           // RNE
  unsigned u = __builtin_bit_cast(unsigned, f);
  u += 0x7FFFu + ((u >> 16) & 1u);
  return (unsigned short)(u >> 16);
}
__device__ inline float bf2f(unsigned short s) {
  return __builtin_bit_cast(float, (unsigned)s << 16);
}
__device__ inline float fsig(float x) {
  return __builtin_amdgcn_rcpf(1.f + __builtin_amdgcn_exp2f(-1.442695041f * x));
}
__device__ inline float ftanh(float x) {
  return 2.f * __builtin_amdgcn_rcpf(1.f + __builtin_amdgcn_exp2f(-2.885390082f * x)) - 1.f;
}
__device__ inline bf16x8 pack8(f32x4 a, f32x4 b) {
  bf16x8 r;
  r[0]=(short)f2bf(a[0]); r[1]=(short)f2bf(a[1]); r[2]=(short)f2bf(a[2]); r[3]=(short)f2bf(a[3]);
  r[4]=(short)f2bf(b[0]); r[5]=(short)f2bf(b[1]); r[6]=(short)f2bf(b[2]); r[7]=(short)f2bf(b[3]);
  return r;
}
// LDS-only barrier: does NOT drain vmcnt.
__device__ inline void bar_lds() {
  asm volatile("s_waitcnt lgkmcnt(0)\n\ts_barrier" ::: "memory");
}
__device__ inline void ystore8(unsigned short* p, unsigned long long v) {
  __hip_atomic_store((unsigned long long*)p, v, __ATOMIC_RELAXED, __HIP_MEMORY_SCOPE_AGENT);
}

__global__ void init_flags(int* f) { if (threadIdx.x < 64) f[threadIdx.x] = 0; }

__global__ __launch_bounds__(512) void lstm_fused(
    const float* __restrict__ x,
    const float* __restrict__ h0, const float* __restrict__ c0,
    const float* __restrict__ Wih0, const float* __restrict__ Whh0,
    const float* __restrict__ bih0, const float* __restrict__ bhh0,
    const float* __restrict__ Wih1, const float* __restrict__ Whh1,
    const float* __restrict__ bih1, const float* __restrict__ bhh1,
    const float* __restrict__ Wih2, const float* __restrict__ Whh2,
    const float* __restrict__ bih2, const float* __restrict__ bhh2,
    const float* __restrict__ Wout, const float* __restrict__ boutp,
    unsigned short* __restrict__ y0, unsigned short* __restrict__ y1,
    float* __restrict__ outp, float* __restrict__ hN, float* __restrict__ cN,
    int* __restrict__ flags)
{
  __shared__ __align__(16) char xqls[NB * BSTR];   // xg chunk [b][t][j][gate]
  __shared__ __align__(16) char hA[2 * 1024];      // h dbuf, compressed A-order
  __shared__ __align__(16) char yst[NB * YSTR];    // per-chunk h stage [b][u][j]
  __shared__ __align__(16) char ystage[16384];     // A-tile stage [b][row][256B], row-XOR-swizzled
  __shared__ int rdyf;                              // prefetch-ready broadcast

  const int tid = threadIdx.x, wave = tid >> 6, lane = tid & 63;
  const int quad = lane >> 4, l15 = lane & 15;
  const int layer = blockIdx.x / NG, g = blockIdx.x % NG;
  const int bg0 = g * NB;
  const int gb = bg0 + quad;
  const int j = wave * 16 + l15;

  const float *Wih, *Whh, *bih, *bhh;
  const unsigned short* yin = nullptr;
  unsigned short* yout = nullptr;
  if (layer == 0)      { Wih = Wih0; Whh = Whh0; bih = bih0; bhh = bhh0; yout = y0; }
  else if (layer == 1) { Wih = Wih1; Whh = Whh1; bih = bih1; bhh = bhh1; yin = y0; yout = y1; }
  else                 { Wih = Wih2; Whh = Whh2; bih = bih2; bhh = bhh2; yin = y1; }
  const int Kin = (layer == 0) ? DD : HH;
  const int* fp = flags + (layer > 0 ? (layer - 1) * NG + g : 0);

  // Whh B-frags: tile n = q*128 + j, k = quad*8 + kc*32 + e
  bf16x8 bwh[4][4];
#pragma unroll
  for (int q = 0; q < 4; ++q)
#pragma unroll
    for (int kc = 0; kc < 4; ++kc) {
      const float* p = Whh + (size_t)(q * 128 + j) * HH + quad * 8 + kc * 32;
      bwh[q][kc] = pack8(*(const f32x4*)p, *(const f32x4*)(p + 4));
    }
  // Wih B-frags (K = 64 or 128)
  bf16x8 bwi[4][4];
#pragma unroll
  for (int q = 0; q < 4; ++q)
    for (int kc = 0; kc < Kin / 32; ++kc) {
      const float* p = Wih + (size_t)(q * 128 + j) * Kin + quad * 8 + kc * 32;
      bwi[q][kc] = pack8(*(const f32x4*)p, *(const f32x4*)(p + 4));
    }
  float bs[4];
#pragma unroll
  for (int q = 0; q < 4; ++q) bs[q] = bih[q * 128 + j] + bhh[q * 128 + j];

  // compressed h layout: h[b][k] at byte
  //   (k>>5)*256 + (((k>>3)&3)*4 + b)*16 + (k&7)*2
  int off_w = (wave >> 1) * 256 + (((((wave & 1) << 1) | (l15 >> 3)) * 4) + quad) * 16 + (l15 & 7) * 2;
  int off_r = (quad * 4 + (l15 >> 2)) * 16;

  // A-tile stage geometry: row byte-length 256 for BOTH y (128 bf16) and
  // x (64 f32). Writer: thread covers 32B. Swizzle: byte ^= (row&7)<<4.
  const int stg_b = tid >> 7, stg_u = (tid >> 3) & 15, stg_p = tid & 7;
  const int swz_w = (stg_u & 7) << 4;
  const int wr0 = stg_b * 4096 + stg_u * 256 + ((stg_p * 32) ^ swz_w);
  const int wr1 = stg_b * 4096 + stg_u * 256 + ((stg_p * 32 + 16) ^ swz_w);
  const int swz_r = (l15 & 7) << 4;

  const float* h0l = h0 + (size_t)layer * BATCH * HH;
  const float* c0l = c0 + (size_t)layer * BATCH * HH;
  *(unsigned short*)(hA + off_w) = f2bf(h0l[(size_t)gb * HH + j]);
  float cc = c0l[(size_t)gb * HH + j];

  // projection weights (layer 2): Wout[lg*16 .. lg*16+15] per lane group
  f32x4 wvp0 = {0,0,0,0}, wvp1 = {0,0,0,0}, wvp2 = {0,0,0,0}, wvp3 = {0,0,0,0};
  float ob = 0.f;
  if (layer == 2) {
    const float* wp = Wout + (lane & 7) * 16;
    wvp0 = *(const f32x4*)(wp + 0);
    wvp1 = *(const f32x4*)(wp + 4);
    wvp2 = *(const f32x4*)(wp + 8);
    wvp3 = *(const f32x4*)(wp + 12);
    ob = boutp[0];
  }

  __syncthreads();

  const f32x4 z4 = {0.f, 0.f, 0.f, 0.f};
  float hv = 0.f;
  const int yst_w = quad * YSTR + j * 2;   // + u*256 per step
  int havepf = 0;

  for (int ck = 0; ck < NCK; ++ck) {
    int t0 = ck * CH;

    // ---- ensure ystage holds this chunk's A-tile ----
    if (!havepf) {
      if (layer > 0) {
        if (tid == 0) {
          while (__hip_atomic_load(fp, __ATOMIC_ACQUIRE, __HIP_MEMORY_SCOPE_AGENT) <= ck)
            __builtin_amdgcn_s_sleep(1);
        }
        __syncthreads();
      }
      u32x4 s0v, s1v;
      if (layer == 0) {
        const float* gp = x + ((size_t)(bg0 + stg_b) * TT + t0 + stg_u) * DD + stg_p * 8;
        asm volatile("global_load_dwordx4 %0, %2, off\n\t"
                     "global_load_dwordx4 %1, %2, off offset:16\n\t"
                     "s_waitcnt vmcnt(0)"
                     : "=&v"(s0v), "=&v"(s1v) : "v"(gp) : "memory");
      } else {
        const unsigned short* gp = yin + ((size_t)(bg0 + stg_b) * TT + t0 + stg_u) * HH + stg_p * 16;
        asm volatile("global_load_dwordx4 %0, %2, off sc0 sc1\n\t"
                     "global_load_dwordx4 %1, %2, off offset:16 sc0 sc1\n\t"
                     "s_waitcnt vmcnt(0)"
                     : "=&v"(s0v), "=&v"(s1v) : "v"(gp) : "memory");
      }
      *(u32x4*)(ystage + wr0) = s0v;
      *(u32x4*)(ystage + wr1) = s1v;
      bar_lds();
    }
    // (havepf path: stage writes happened at step 10 last chunk; step
    //  barriers since then made them visible — start GEMM immediately.)

    // ---- fused chunk GEMM from LDS stage: 4 M-tiles ----
    if (layer == 0) {
#pragma unroll
      for (int mt = 0; mt < 4; ++mt) {
        const char* rb = ystage + mt * 4096 + l15 * 256;
        f32x4 x0 = *(const f32x4*)(rb + ((quad * 32) ^ swz_r));
        f32x4 x1 = *(const f32x4*)(rb + ((quad * 32 + 16) ^ swz_r));
        f32x4 x2 = *(const f32x4*)(rb + ((128 + quad * 32) ^ swz_r));
        f32x4 x3 = *(const f32x4*)(rb + ((128 + quad * 32 + 16) ^ swz_r));
        bf16x8 af0 = pack8(x0, x1);
        bf16x8 af1 = pack8(x2, x3);
        f32x4 acc[4];
#pragma unroll
        for (int q = 0; q < 4; ++q) acc[q] = __builtin_amdgcn_mfma_f32_16x16x32_bf16(af0, bwi[q][0], z4, 0, 0, 0);
#pragma unroll
        for (int q = 0; q < 4; ++q) acc[q] = __builtin_amdgcn_mfma_f32_16x16x32_bf16(af1, bwi[q][1], acc[q], 0, 0, 0);
        char* base = xqls + mt * BSTR + (quad * 4) * 1024 + j * 8;
#pragma unroll
        for (int r = 0; r < 4; ++r) {
          bf16x4 o;
#pragma unroll
          for (int q = 0; q < 4; ++q) o[q] = (short)f2bf(acc[q][r] + bs[q]);
          *(bf16x4*)(base + r * 1024) = o;
        }
      }
    } else {
#pragma unroll
      for (int mt = 0; mt < 4; ++mt) {
        const char* rb = ystage + mt * 4096 + l15 * 256;
        bf16x8 a4[4];
#pragma unroll
        for (int kc = 0; kc < 4; ++kc)
          a4[kc] = *(const bf16x8*)(rb + ((quad * 16 + kc * 64) ^ swz_r));
        f32x4 acc[4];
#pragma unroll
        for (int q = 0; q < 4; ++q) acc[q] = __builtin_amdgcn_mfma_f32_16x16x32_bf16(a4[0], bwi[q][0], z4, 0, 0, 0);
#pragma unroll
        for (int kc = 1; kc < 4; ++kc)
#pragma unroll
          for (int q = 0; q < 4; ++q) acc[q] = __builtin_amdgcn_mfma_f32_16x16x32_bf16(a4[kc], bwi[q][kc], acc[q], 0, 0, 0);
        char* base = xqls + mt * BSTR + (quad * 4) * 1024 + j * 8;
#pragma unroll
        for (int r = 0; r < 4; ++r) {
          bf16x4 o;
#pragma unroll
          for (int q = 0; q < 4; ++q) o[q] = (short)f2bf(acc[q][r] + bs[q]);
          *(bf16x4*)(base + r * 1024) = o;
        }
      }
    }
    bar_lds();

    // ---- CH recurrence steps (uniform body) + hidden prefetch ----
    unsigned fvp = 0;
    u32x4 pf0, pf1;
#pragma unroll
    for (int u = 0; u < CH; ++u) {
      char* cur = hA + ((u & 1) << 10);          // CH even -> u&1 == t&1
      char* nxt = hA + (((u + 1) & 1) << 10);

      bf16x8 a0 = *(const bf16x8*)(cur + off_r);
      bf16x8 a1 = *(const bf16x8*)(cur + 256 + off_r);
      bf16x8 a2 = *(const bf16x8*)(cur + 512 + off_r);
      bf16x8 a3 = *(const bf16x8*)(cur + 768 + off_r);
      bf16x4 xq4 = *(const bf16x4*)(xqls + quad * BSTR + u * 1024 + j * 8);

      f32x4 c01[4], c23[4];
#pragma unroll
      for (int q = 0; q < 4; ++q) c01[q] = __builtin_amdgcn_mfma_f32_16x16x32_bf16(a0, bwh[q][0], z4, 0, 0, 0);
#pragma unroll
      for (int q = 0; q < 4; ++q) c23[q] = __builtin_amdgcn_mfma_f32_16x16x32_bf16(a2, bwh[q][2], z4, 0, 0, 0);
#pragma unroll
      for (int q = 0; q < 4; ++q) c01[q] = __builtin_amdgcn_mfma_f32_16x16x32_bf16(a1, bwh[q][1], c01[q], 0, 0, 0);
#pragma unroll
      for (int q = 0; q < 4; ++q) c23[q] = __builtin_amdgcn_mfma_f32_16x16x32_bf16(a3, bwh[q][3], c23[q], 0, 0, 0);

      float gi = fsig(c01[0][0] + c23[0][0] + bf2f((unsigned short)xq4[0]));
      float gf = fsig(c01[1][0] + c23[1][0] + bf2f((unsigned short)xq4[1]));
      float gg = ftanh(c01[2][0] + c23[2][0] + bf2f((unsigned short)xq4[2]));
      float go = fsig(c01[3][0] + c23[3][0] + bf2f((unsigned short)xq4[3]));
      cc = gf * cc + gi * gg;
      hv = go * ftanh(cc);
      unsigned short hb = f2bf(hv);
      *(unsigned short*)(nxt + off_w) = hb;                 // h exchange
      *(unsigned short*)(yst + yst_w + u * 256) = hb;       // y/proj stage

      // ---- prefetch machinery (off the per-step latency chain) ----
      if (u == 0 && layer > 0 && ck + 1 < NCK) {
        asm volatile("global_load_dword %0, %1, off sc0 sc1"
                     : "=&v"(fvp) : "v"(fp) : "memory");
      }
      if (u == 2 && layer > 0 && ck + 1 < NCK) {
        // Rule-#18 fix: tie fvp THROUGH the waitcnt ("+v" = def-use edge)
        // so the register-only compare below cannot be scheduled before
        // the wait; sched_barrier(0) as the prescribed fence.
        asm volatile("s_waitcnt vmcnt(0)" : "+v"(fvp) :: "memory");
        __builtin_amdgcn_sched_barrier(0);
        int rdy = __any((int)fvp > ck + 1) ? 1 : 0;         // producer >= ck+2
        if (tid == 0) rdyf = rdy;                           // visible after this bar_lds
      }
      if (u == 3) {
        havepf = 0;
        if (ck + 1 < NCK) {
          if (layer == 0) {
            const float* gp = x + ((size_t)(bg0 + stg_b) * TT + t0 + CH + stg_u) * DD + stg_p * 8;
            asm volatile("global_load_dwordx4 %0, %2, off\n\t"
                         "global_load_dwordx4 %1, %2, off offset:16"
                         : "=&v"(pf0), "=&v"(pf1) : "v"(gp) : "memory");
            havepf = 1;
          } else if (rdyf) {
            const unsigned short* gp = yin + ((size_t)(bg0 + stg_b) * TT + t0 + CH + stg_u) * HH + stg_p * 16;
            asm volatile("global_load_dwordx4 %0, %2, off sc0 sc1\n\t"
                         "global_load_dwordx4 %1, %2, off offset:16 sc0 sc1"
                         : "=&v"(pf0), "=&v"(pf1) : "v"(gp) : "memory");
            havepf = 1;
          }
        }
      }
      if (u == 10 && havepf) {
        asm volatile("s_waitcnt vmcnt(0)" ::: "memory");    // prefetch loads done
        __builtin_amdgcn_sched_barrier(0);                  // defensive (rule #18)
        *(u32x4*)(ystage + wr0) = pf0;                      // visible via step barriers
        *(u32x4*)(ystage + wr1) = pf1;
      }
      bar_lds();
    }

    // ---- chunk epilogue ----
    if (layer < 2) {
      // bulk y export: 16 KB stage -> global via wide agent-scope stores
#pragma unroll
      for (int s = 0; s < 2; ++s) {
        int seg = tid + s * 512;
        int b = seg >> 8, u = (seg >> 4) & 15, part = seg & 15;
        U8 v; v.v = *(const bf16x8*)(yst + b * YSTR + u * 256 + part * 16);
        size_t di = ((size_t)(bg0 + b) * TT + t0 + u) * HH + part * 8;
        ystore8(yout + di, v.q[0]);
        ystore8(yout + di + 4, v.q[1]);
      }
      asm volatile("s_waitcnt vmcnt(0)" ::: "memory");
      __syncthreads();
      if (tid == 0)
        __hip_atomic_store(flags + layer * NG + g, ck + 1,
                           __ATOMIC_RELAXED, __HIP_MEMORY_SCOPE_AGENT);
    } else {
      // projection: 64 outputs (4 b x 16 u), 8 lanes per output
      int og = lane >> 3, lg = lane & 7;
      int o = wave * 8 + og;
      int b = o >> 4, u = o & 15;
      const char* sp = yst + b * YSTR + u * 256 + lg * 32;
      bf16x8 ha = *(const bf16x8*)sp;
      bf16x8 hbv = *(const bf16x8*)(sp + 16);
      float s = 0.f;
#pragma unroll
      for (int e = 0; e < 4; ++e) s += bf2f((unsigned short)ha[e]) * wvp0[e];
#pragma unroll
      for (int e = 0; e < 4; ++e) s += bf2f((unsigned short)ha[e + 4]) * wvp1[e];
#pragma unroll
      for (int e = 0; e < 4; ++e) s += bf2f((unsigned short)hbv[e]) * wvp2[e];
#pragma unroll
      for (int e = 0; e < 4; ++e) s += bf2f((unsigned short)hbv[e + 4]) * wvp3[e];
      s += __shfl_xor(s, 1);
      s += __shfl_xor(s, 2);
      s += __shfl_xor(s, 4);
      if (lg == 0) outp[(size_t)(bg0 + b) * TT + t0 + u] = fmaxf(s + ob, 0.f);
      // yst reads drain at the next GEMM-phase bar_lds before step-0
      // overwrites yst; xqls writes are a different region.
    }
  }

  float* hNl = hN + (size_t)layer * BATCH * HH;
  float* cNl = cN + (size_t)layer * BATCH * HH;
  hNl[(size_t)gb * HH + j] = hv;
  cNl[(size_t)gb * HH + j] = cc;
}

// ---------------- launch ----------------
extern "C" void kernel_launch(void* const* d_in, const int* in_sizes, int n_in,
                              void* d_out, int out_size, void* d_ws, size_t ws_size,
                              hipStream_t stream) {
  const float* x  = (const float*)d_in[0];
  const float* h0 = (const float*)d_in[1];
  const float* c0 = (const float*)d_in[2];
  const float* Wih[3] = {(const float*)d_in[3], (const float*)d_in[7],  (const float*)d_in[11]};
  const float* Whh[3] = {(const float*)d_in[4], (const float*)d_in[8],  (const float*)d_in[12]};
  const float* bih[3] = {(const float*)d_in[5], (const float*)d_in[9],  (const float*)d_in[13]};
  const float* bhh[3] = {(const float*)d_in[6], (const float*)d_in[10], (const float*)d_in[14]};
  const float* Wout = (const float*)d_in[15];
  const float* bout = (const float*)d_in[16];

  float* outp = (float*)d_out;                 // [B][T]
  float* hN = outp + BATCH * TT;               // [L][B][H]
  float* cN = hN + 3 * BATCH * HH;

  char* ws = (char*)d_ws;
  int* flags = (int*)ws;                                            // 64 ints
  unsigned short* y0 = (unsigned short*)(ws + 4096);                // 32 MB
  unsigned short* y1 = (unsigned short*)(ws + 4096 + (size_t)BATCH * TT * HH * 2);

  init_flags<<<1, 64, 0, stream>>>(flags);
  lstm_fused<<<3 * NG, 512, 0, stream>>>(
      x, h0, c0,
      Wih[0], Whh[0], bih[0], bhh[0],
      Wih[1], Whh[1], bih[1], bhh[1],
      Wih[2], Whh[2], bih[2], bhh[2],
      Wout, bout, y0, y1, outp, hN, cN, flags);
}

// Round 7
// 1114.442 us; speedup vs baseline: 1.5353x; 1.0058x over previous
//
#include <hip/hip_runtime.h>

// LSTM B=128,T=1024,H=128,D=64,L=3 — fused, layer-pipelined, R13.
// R13 = R11's bench-proven prefetch schedule + R12's change (A) only.
//  (A) Unified h exchange (from R12): the per-step h double-store (hA
//      compressed + yst linear) was redundant — the MFMA A-frag
//      (h[b=l15>>2][k=kc*32+quad*8+e], 16B contiguous) is directly
//      addressable in yst's linear [b][u][j] layout at b*YSTR + row*256 +
//      quad*16 + kc*64; 4 lanes/group read the SAME 16B (LDS broadcast,
//      conflict-free). hA + one ds_write/step deleted. Step u reads row
//      (u+15)&15; h0 seeded into row 15.
//  R12's (B)/(C) prefetch re-schedule REVERTED: R12 failed (absmax 0.028)
//      and the audit points at the stretched in-flight inline-asm register
//      windows (pf/fvp live across 8 unrolled step bodies; an allocator
//      copy/spill of an in-flight register reads garbage — allocation-
//      dependent, not fence-fixable). R11's narrower windows (flag u0,
//      tie-test u2, issue u3, drain u10) passed on hardware; restored
//      verbatim for clean attribution.
// R11 base: 16KB swizzled LDS A-tile stage loaded once per WG, chunk-top
// skips poll/sync when prefetched; batched sc0sc1 loads; chunk-end bulk y
// export + projection; uniform step body; 96 WGs = 3 layers x 32 groups,
// CH=16, lgkm-only barriers, Whh+Wih B-frags in registers.

#define BATCH 128
#define TT    1024
#define HH    128
#define DD    64
#define NB    4
#define CH    16                // chunk steps
#define NG    32                // batch groups per layer
#define NCK   (TT / CH)
#define BSTR  (CH * 1024 + 8)   // xg LDS bytes per batch
#define YSTR  (CH * 256 + 32)   // y/h stage LDS bytes per batch (+32 pad)

typedef __attribute__((ext_vector_type(4))) float f32x4;
typedef __attribute__((ext_vector_type(8))) short bf16x8;
typedef __attribute__((ext_vector_type(4))) short bf16x4;
typedef __attribute__((ext_vector_type(4))) unsigned u32x4;

union U8 { unsigned long long q[2]; bf16x8 v; };

__device__ inline unsigned short f2bf(float f) {           // RNE
  unsigned u = __builtin_bit_cast(unsigned, f);
  u += 0x7FFFu + ((u >> 16) & 1u);
  return (unsigned short)(u >> 16);
}
__device__ inline float bf2f(unsigned short s) {
  return __builtin_bit_cast(float, (unsigned)s << 16);
}
__device__ inline float fsig(float x) {
  return __builtin_amdgcn_rcpf(1.f + __builtin_amdgcn_exp2f(-1.442695041f * x));
}
__device__ inline float ftanh(float x) {
  return 2.f * __builtin_amdgcn_rcpf(1.f + __builtin_amdgcn_exp2f(-2.885390082f * x)) - 1.f;
}
__device__ inline bf16x8 pack8(f32x4 a, f32x4 b) {
  bf16x8 r;
  r[0]=(short)f2bf(a[0]); r[1]=(short)f2bf(a[1]); r[2]=(short)f2bf(a[2]); r[3]=(short)f2bf(a[3]);
  r[4]=(short)f2bf(b[0]); r[5]=(short)f2bf(b[1]); r[6]=(short)f2bf(b[2]); r[7]=(short)f2bf(b[3]);
  return r;
}
// LDS-only barrier: does NOT drain vmcnt.
__device__ inline void bar_lds() {
  asm volatile("s_waitcnt lgkmcnt(0)\n\ts_barrier" ::: "memory");
}
__device__ inline void ystore8(unsigned short* p, unsigned long long v) {
  __hip_atomic_store((unsigned long long*)p, v, __ATOMIC_RELAXED, __HIP_MEMORY_SCOPE_AGENT);
}

__global__ void init_flags(int* f) { if (threadIdx.x < 64) f[threadIdx.x] = 0; }

__global__ __launch_bounds__(512) void lstm_fused(
    const float* __restrict__ x,
    const float* __restrict__ h0, const float* __restrict__ c0,
    const float* __restrict__ Wih0, const float* __restrict__ Whh0,
    const float* __restrict__ bih0, const float* __restrict__ bhh0,
    const float* __restrict__ Wih1, const float* __restrict__ Whh1,
    const float* __restrict__ bih1, const float* __restrict__ bhh1,
    const float* __restrict__ Wih2, const float* __restrict__ Whh2,
    const float* __restrict__ bih2, const float* __restrict__ bhh2,
    const float* __restrict__ Wout, const float* __restrict__ boutp,
    unsigned short* __restrict__ y0, unsigned short* __restrict__ y1,
    float* __restrict__ outp, float* __restrict__ hN, float* __restrict__ cN,
    int* __restrict__ flags)
{
  __shared__ __align__(16) char xqls[NB * BSTR];   // xg chunk [b][t][j][gate]
  __shared__ __align__(16) char yst[NB * YSTR];    // h stage [b][u][j] — exchange + export + proj
  __shared__ __align__(16) char ystage[16384];     // A-tile stage [b][row][256B], row-XOR-swizzled
  __shared__ int rdyf;                              // prefetch-ready broadcast

  const int tid = threadIdx.x, wave = tid >> 6, lane = tid & 63;
  const int quad = lane >> 4, l15 = lane & 15;
  const int layer = blockIdx.x / NG, g = blockIdx.x % NG;
  const int bg0 = g * NB;
  const int gb = bg0 + quad;
  const int j = wave * 16 + l15;

  const float *Wih, *Whh, *bih, *bhh;
  const unsigned short* yin = nullptr;
  unsigned short* yout = nullptr;
  if (layer == 0)      { Wih = Wih0; Whh = Whh0; bih = bih0; bhh = bhh0; yout = y0; }
  else if (layer == 1) { Wih = Wih1; Whh = Whh1; bih = bih1; bhh = bhh1; yin = y0; yout = y1; }
  else                 { Wih = Wih2; Whh = Whh2; bih = bih2; bhh = bhh2; yin = y1; }
  const int Kin = (layer == 0) ? DD : HH;
  const int* fp = flags + (layer > 0 ? (layer - 1) * NG + g : 0);

  // Whh B-frags: tile n = q*128 + j, k = quad*8 + kc*32 + e
  bf16x8 bwh[4][4];
#pragma unroll
  for (int q = 0; q < 4; ++q)
#pragma unroll
    for (int kc = 0; kc < 4; ++kc) {
      const float* p = Whh + (size_t)(q * 128 + j) * HH + quad * 8 + kc * 32;
      bwh[q][kc] = pack8(*(const f32x4*)p, *(const f32x4*)(p + 4));
    }
  // Wih B-frags (K = 64 or 128)
  bf16x8 bwi[4][4];
#pragma unroll
  for (int q = 0; q < 4; ++q)
    for (int kc = 0; kc < Kin / 32; ++kc) {
      const float* p = Wih + (size_t)(q * 128 + j) * Kin + quad * 8 + kc * 32;
      bwi[q][kc] = pack8(*(const f32x4*)p, *(const f32x4*)(p + 4));
    }
  float bs[4];
#pragma unroll
  for (int q = 0; q < 4; ++q) bs[q] = bih[q * 128 + j] + bhh[q * 128 + j];

  // A-tile stage geometry: row byte-length 256 for BOTH y (128 bf16) and
  // x (64 f32). Writer: thread covers 32B. Swizzle: byte ^= (row&7)<<4.
  const int stg_b = tid >> 7, stg_u = (tid >> 3) & 15, stg_p = tid & 7;
  const int swz_w = (stg_u & 7) << 4;
  const int wr0 = stg_b * 4096 + stg_u * 256 + ((stg_p * 32) ^ swz_w);
  const int wr1 = stg_b * 4096 + stg_u * 256 + ((stg_p * 32 + 16) ^ swz_w);
  const int swz_r = (l15 & 7) << 4;

  const float* h0l = h0 + (size_t)layer * BATCH * HH;
  const float* c0l = c0 + (size_t)layer * BATCH * HH;
  // seed h0 into yst row 15 (step 0 reads row (0+15)&15 = 15)
  *(unsigned short*)(yst + quad * YSTR + 15 * 256 + j * 2) = f2bf(h0l[(size_t)gb * HH + j]);
  float cc = c0l[(size_t)gb * HH + j];

  // projection weights (layer 2): Wout[lg*16 .. lg*16+15] per lane group
  f32x4 wvp0 = {0,0,0,0}, wvp1 = {0,0,0,0}, wvp2 = {0,0,0,0}, wvp3 = {0,0,0,0};
  float ob = 0.f;
  if (layer == 2) {
    const float* wp = Wout + (lane & 7) * 16;
    wvp0 = *(const f32x4*)(wp + 0);
    wvp1 = *(const f32x4*)(wp + 4);
    wvp2 = *(const f32x4*)(wp + 8);
    wvp3 = *(const f32x4*)(wp + 12);
    ob = boutp[0];
  }

  __syncthreads();

  const f32x4 z4 = {0.f, 0.f, 0.f, 0.f};
  float hv = 0.f;
  const int yst_w = quad * YSTR + j * 2;            // + u*256 per step
  const char* abase0 = yst + (l15 >> 2) * YSTR + quad * 16;  // + row*256, +kc*64
  int havepf = 0;

  for (int ck = 0; ck < NCK; ++ck) {
    int t0 = ck * CH;

    // ---- ensure ystage holds this chunk's A-tile ----
    if (!havepf) {
      if (layer > 0) {
        if (tid == 0) {
          while (__hip_atomic_load(fp, __ATOMIC_ACQUIRE, __HIP_MEMORY_SCOPE_AGENT) <= ck)
            __builtin_amdgcn_s_sleep(1);
        }
        __syncthreads();
      }
      u32x4 s0v, s1v;
      if (layer == 0) {
        const float* gp = x + ((size_t)(bg0 + stg_b) * TT + t0 + stg_u) * DD + stg_p * 8;
        asm volatile("global_load_dwordx4 %0, %2, off\n\t"
                     "global_load_dwordx4 %1, %2, off offset:16\n\t"
                     "s_waitcnt vmcnt(0)"
                     : "=&v"(s0v), "=&v"(s1v) : "v"(gp) : "memory");
      } else {
        const unsigned short* gp = yin + ((size_t)(bg0 + stg_b) * TT + t0 + stg_u) * HH + stg_p * 16;
        asm volatile("global_load_dwordx4 %0, %2, off sc0 sc1\n\t"
                     "global_load_dwordx4 %1, %2, off offset:16 sc0 sc1\n\t"
                     "s_waitcnt vmcnt(0)"
                     : "=&v"(s0v), "=&v"(s1v) : "v"(gp) : "memory");
      }
      *(u32x4*)(ystage + wr0) = s0v;
      *(u32x4*)(ystage + wr1) = s1v;
      bar_lds();
    }
    // (havepf path: stage writes happened at step 10 last chunk; step
    //  barriers since then made them visible — start GEMM immediately.)

    // ---- fused chunk GEMM from LDS stage: 4 M-tiles ----
    if (layer == 0) {
#pragma unroll
      for (int mt = 0; mt < 4; ++mt) {
        const char* rb = ystage + mt * 4096 + l15 * 256;
        f32x4 x0 = *(const f32x4*)(rb + ((quad * 32) ^ swz_r));
        f32x4 x1 = *(const f32x4*)(rb + ((quad * 32 + 16) ^ swz_r));
        f32x4 x2 = *(const f32x4*)(rb + ((128 + quad * 32) ^ swz_r));
        f32x4 x3 = *(const f32x4*)(rb + ((128 + quad * 32 + 16) ^ swz_r));
        bf16x8 af0 = pack8(x0, x1);
        bf16x8 af1 = pack8(x2, x3);
        f32x4 acc[4];
#pragma unroll
        for (int q = 0; q < 4; ++q) acc[q] = __builtin_amdgcn_mfma_f32_16x16x32_bf16(af0, bwi[q][0], z4, 0, 0, 0);
#pragma unroll
        for (int q = 0; q < 4; ++q) acc[q] = __builtin_amdgcn_mfma_f32_16x16x32_bf16(af1, bwi[q][1], acc[q], 0, 0, 0);
        char* base = xqls + mt * BSTR + (quad * 4) * 1024 + j * 8;
#pragma unroll
        for (int r = 0; r < 4; ++r) {
          bf16x4 o;
#pragma unroll
          for (int q = 0; q < 4; ++q) o[q] = (short)f2bf(acc[q][r] + bs[q]);
          *(bf16x4*)(base + r * 1024) = o;
        }
      }
    } else {
#pragma unroll
      for (int mt = 0; mt < 4; ++mt) {
        const char* rb = ystage + mt * 4096 + l15 * 256;
        bf16x8 a4[4];
#pragma unroll
        for (int kc = 0; kc < 4; ++kc)
          a4[kc] = *(const bf16x8*)(rb + ((quad * 16 + kc * 64) ^ swz_r));
        f32x4 acc[4];
#pragma unroll
        for (int q = 0; q < 4; ++q) acc[q] = __builtin_amdgcn_mfma_f32_16x16x32_bf16(a4[0], bwi[q][0], z4, 0, 0, 0);
#pragma unroll
        for (int kc = 1; kc < 4; ++kc)
#pragma unroll
          for (int q = 0; q < 4; ++q) acc[q] = __builtin_amdgcn_mfma_f32_16x16x32_bf16(a4[kc], bwi[q][kc], acc[q], 0, 0, 0);
        char* base = xqls + mt * BSTR + (quad * 4) * 1024 + j * 8;
#pragma unroll
        for (int r = 0; r < 4; ++r) {
          bf16x4 o;
#pragma unroll
          for (int q = 0; q < 4; ++q) o[q] = (short)f2bf(acc[q][r] + bs[q]);
          *(bf16x4*)(base + r * 1024) = o;
        }
      }
    }
    bar_lds();

    // ---- CH recurrence steps (uniform body) + hidden prefetch (R11 sched) ----
    unsigned fvp = 0;
    u32x4 pf0, pf1;
#pragma unroll
    for (int u = 0; u < CH; ++u) {
      // A-frags directly from yst row (u+15)&15 (4-lane broadcast reads)
      const char* ab = abase0 + (((u + 15) & 15) * 256);
      bf16x8 a0 = *(const bf16x8*)(ab);
      bf16x8 a1 = *(const bf16x8*)(ab + 64);
      bf16x8 a2 = *(const bf16x8*)(ab + 128);
      bf16x8 a3 = *(const bf16x8*)(ab + 192);
      bf16x4 xq4 = *(const bf16x4*)(xqls + quad * BSTR + u * 1024 + j * 8);

      f32x4 c01[4], c23[4];
#pragma unroll
      for (int q = 0; q < 4; ++q) c01[q] = __builtin_amdgcn_mfma_f32_16x16x32_bf16(a0, bwh[q][0], z4, 0, 0, 0);
#pragma unroll
      for (int q = 0; q < 4; ++q) c23[q] = __builtin_amdgcn_mfma_f32_16x16x32_bf16(a2, bwh[q][2], z4, 0, 0, 0);
#pragma unroll
      for (int q = 0; q < 4; ++q) c01[q] = __builtin_amdgcn_mfma_f32_16x16x32_bf16(a1, bwh[q][1], c01[q], 0, 0, 0);
#pragma unroll
      for (int q = 0; q < 4; ++q) c23[q] = __builtin_amdgcn_mfma_f32_16x16x32_bf16(a3, bwh[q][3], c23[q], 0, 0, 0);

      float gi = fsig(c01[0][0] + c23[0][0] + bf2f((unsigned short)xq4[0]));
      float gf = fsig(c01[1][0] + c23[1][0] + bf2f((unsigned short)xq4[1]));
      float gg = ftanh(c01[2][0] + c23[2][0] + bf2f((unsigned short)xq4[2]));
      float go = fsig(c01[3][0] + c23[3][0] + bf2f((unsigned short)xq4[3]));
      cc = gf * cc + gi * gg;
      hv = go * ftanh(cc);
      unsigned short hb = f2bf(hv);
      *(unsigned short*)(yst + yst_w + u * 256) = hb;   // single h store (exchange+stage)

      // ---- prefetch machinery (R11 schedule, bench-proven) ----
      if (u == 0 && layer > 0 && ck + 1 < NCK) {
        asm volatile("global_load_dword %0, %1, off sc0 sc1"
                     : "=&v"(fvp) : "v"(fp) : "memory");
      }
      if (u == 2 && layer > 0 && ck + 1 < NCK) {
        // rule-#18 pattern: value tied THROUGH the waitcnt + sched fence
        asm volatile("s_waitcnt vmcnt(0)" : "+v"(fvp) :: "memory");
        __builtin_amdgcn_sched_barrier(0);
        int rdy = __any((int)fvp > ck + 1) ? 1 : 0;     // producer >= ck+2
        if (tid == 0) rdyf = rdy;                       // visible after this bar_lds
      }
      if (u == 3) {
        havepf = 0;
        if (ck + 1 < NCK) {
          if (layer == 0) {
            const float* gp = x + ((size_t)(bg0 + stg_b) * TT + t0 + CH + stg_u) * DD + stg_p * 8;
            asm volatile("global_load_dwordx4 %0, %2, off\n\t"
                         "global_load_dwordx4 %1, %2, off offset:16"
                         : "=&v"(pf0), "=&v"(pf1) : "v"(gp) : "memory");
            havepf = 1;
          } else if (rdyf) {
            const unsigned short* gp = yin + ((size_t)(bg0 + stg_b) * TT + t0 + CH + stg_u) * HH + stg_p * 16;
            asm volatile("global_load_dwordx4 %0, %2, off sc0 sc1\n\t"
                         "global_load_dwordx4 %1, %2, off offset:16 sc0 sc1"
                         : "=&v"(pf0), "=&v"(pf1) : "v"(gp) : "memory");
            havepf = 1;
          }
        }
      }
      if (u == 10 && havepf) {
        asm volatile("s_waitcnt vmcnt(0)" ::: "memory"); // prefetch loads done
        __builtin_amdgcn_sched_barrier(0);               // defensive (rule #18)
        *(u32x4*)(ystage + wr0) = pf0;                   // ds_writes: memory ops,
        *(u32x4*)(ystage + wr1) = pf1;                   // ordered after waitcnt
      }
      bar_lds();
    }

    // ---- chunk epilogue ----
    if (layer < 2) {
      // bulk y export: 16 KB stage -> global via wide agent-scope stores
#pragma unroll
      for (int s = 0; s < 2; ++s) {
        int seg = tid + s * 512;
        int b = seg >> 8, u = (seg >> 4) & 15, part = seg & 15;
        U8 v; v.v = *(const bf16x8*)(yst + b * YSTR + u * 256 + part * 16);
        size_t di = ((size_t)(bg0 + b) * TT + t0 + u) * HH + part * 8;
        ystore8(yout + di, v.q[0]);
        ystore8(yout + di + 4, v.q[1]);
      }
      asm volatile("s_waitcnt vmcnt(0)" ::: "memory");
      __syncthreads();
      if (tid == 0)
        __hip_atomic_store(flags + layer * NG + g, ck + 1,
                           __ATOMIC_RELAXED, __HIP_MEMORY_SCOPE_AGENT);
    } else {
      // projection: 64 outputs (4 b x 16 u), 8 lanes per output
      int og = lane >> 3, lg = lane & 7;
      int o = wave * 8 + og;
      int b = o >> 4, u = o & 15;
      const char* sp = yst + b * YSTR + u * 256 + lg * 32;
      bf16x8 ha = *(const bf16x8*)sp;
      bf16x8 hbv = *(const bf16x8*)(sp + 16);
      float s = 0.f;
#pragma unroll
      for (int e = 0; e < 4; ++e) s += bf2f((unsigned short)ha[e]) * wvp0[e];
#pragma unroll
      for (int e = 0; e < 4; ++e) s += bf2f((unsigned short)ha[e + 4]) * wvp1[e];
#pragma unroll
      for (int e = 0; e < 4; ++e) s += bf2f((unsigned short)hbv[e]) * wvp2[e];
#pragma unroll
      for (int e = 0; e < 4; ++e) s += bf2f((unsigned short)hbv[e + 4]) * wvp3[e];
      s += __shfl_xor(s, 1);
      s += __shfl_xor(s, 2);
      s += __shfl_xor(s, 4);
      if (lg == 0) outp[(size_t)(bg0 + b) * TT + t0 + u] = fmaxf(s + ob, 0.f);
      // yst reads drain at the next GEMM-phase bar_lds before step-0
      // overwrites yst; row 15 (read by step 0) is written only at step 15.
    }
  }

  float* hNl = hN + (size_t)layer * BATCH * HH;
  float* cNl = cN + (size_t)layer * BATCH * HH;
  hNl[(size_t)gb * HH + j] = hv;
  cNl[(size_t)gb * HH + j] = cc;
}

// ---------------- launch ----------------
extern "C" void kernel_launch(void* const* d_in, const int* in_sizes, int n_in,
                              void* d_out, int out_size, void* d_ws, size_t ws_size,
                              hipStream_t stream) {
  const float* x  = (const float*)d_in[0];
  const float* h0 = (const float*)d_in[1];
  const float* c0 = (const float*)d_in[2];
  const float* Wih[3] = {(const float*)d_in[3], (const float*)d_in[7],  (const float*)d_in[11]};
  const float* Whh[3] = {(const float*)d_in[4], (const float*)d_in[8],  (const float*)d_in[12]};
  const float* bih[3] = {(const float*)d_in[5], (const float*)d_in[9],  (const float*)d_in[13]};
  const float* bhh[3] = {(const float*)d_in[6], (const float*)d_in[10], (const float*)d_in[14]};
  const float* Wout = (const float*)d_in[15];
  const float* bout = (const float*)d_in[16];

  float* outp = (float*)d_out;                 // [B][T]
  float* hN = outp + BATCH * TT;               // [L][B][H]
  float* cN = hN + 3 * BATCH * HH;

  char* ws = (char*)d_ws;
  int* flags = (int*)ws;                                            // 64 ints
  unsigned short* y0 = (unsigned short*)(ws + 4096);                // 32 MB
  unsigned short* y1 = (unsigned short*)(ws + 4096 + (size_t)BATCH * TT * HH * 2);

  init_flags<<<1, 64, 0, stream>>>(flags);
  lstm_fused<<<3 * NG, 512, 0, stream>>>(
      x, h0, c0,
      Wih[0], Whh[0], bih[0], bhh[0],
      Wih[1], Whh[1], bih[1], bhh[1],
      Wih[2], Whh[2], bih[2], bhh[2],
      Wout, bout, y0, y1, outp, hN, cN, flags);
}